// Round 1
// baseline (3132.789 us; speedup 1.0000x reference)
//
#include <hip/hip_runtime.h>

// ---------------- constants ----------------
#define NUM_HEADS 32
#define KV_HEADS 8
#define HEAD_DIM 128
#define HIDDEN 4096
#define Q_DIM 4096
#define KV_DIM 1024
#define QKV_DIM 6144
#define GROUP 4
#define BP 4
#define S_LEN 1024
#define BD 64
#define L_CTX 2048
#define RANK 16
#define NA 8
#define TP (BP * S_LEN)      // 4096
#define T_TOT (TP + BD)      // 4160
#define SCALE 0.08838834764831845f
#define LORA_SCALE 0.5f

typedef float fv4 __attribute__((ext_vector_type(4)));
typedef __bf16 bf16x8 __attribute__((ext_vector_type(8)));
typedef unsigned short usv4 __attribute__((ext_vector_type(4)));
typedef unsigned short u16;

__device__ __forceinline__ float b2f(u16 u) {
    unsigned int x = ((unsigned int)u) << 16;
    return __builtin_bit_cast(float, x);
}
__device__ __forceinline__ u16 f2b(float f) {
    unsigned int u = __builtin_bit_cast(unsigned int, f);
    unsigned int r = u + 0x7fffu + ((u >> 16) & 1u);
    return (u16)(r >> 16);
}

// ---------------- workspace layout (bytes) ----------------
#define OFF_QKV  ((size_t)0)                  // 4160*6144*2 = 51,118,080 (bf16) ; reused as attn after K3
#define OFF_ATTN OFF_QKV                      // 4160*4096*2 = 34,078,720 (bf16) alias
#define OFF_T    ((size_t)51118080)           // 4160*48*4
#define OFF_QP   ((size_t)51916800)           // (4,32,1024,128) bf16
#define OFF_KP   ((size_t)85471232)           // (4,8,1024,128) bf16
#define OFF_VP   ((size_t)93859840)           // (4,8,1024,128) bf16
#define OFF_QD   ((size_t)102248448)          // (64,32,128) f32
#define OFF_KD   ((size_t)104345600)          // (64,8,128) f32
#define OFF_VD   ((size_t)104869888)          // (64,8,128) f32
#define OFF_TO   ((size_t)105394176)          // 4160*16*4
#define OFF_COS  ((size_t)105660416)          // 2049*64*4
#define OFF_SIN  ((size_t)106184960)          // 2049*64*4

// ---------------- K0: rope tables ----------------
__global__ void rope_tab_kernel(float* ctab, float* stab) {
    int idx = blockIdx.x * 256 + threadIdx.x;
    if (idx >= 2049 * 64) return;
    int pos = idx >> 6, d = idx & 63;
    float inv = 1.0f / powf(10000.0f, (float)d / 64.0f);
    float f = (float)pos * inv;
    ctab[idx] = cosf(f);
    stab[idx] = sinf(f);
}

// ---------------- K1: LoRA-A ranks (q,k,v) ----------------
// thread = (matrix, token, r): T[t*48 + mat*16 + r] = sum_h x[t][h] * A_mat[a][h][r]
__global__ void lora_a_kernel(const float* __restrict__ x,
                              const float* __restrict__ Aq, const float* __restrict__ Ak,
                              const float* __restrict__ Av,
                              const int* __restrict__ pidx, const int* __restrict__ didx,
                              float* __restrict__ T) {
    int gid = blockIdx.x * 256 + threadIdx.x;
    const int per_mat = T_TOT * RANK;
    if (gid >= 3 * per_mat) return;
    int mat = gid / per_mat;
    int rem = gid - mat * per_mat;
    int t = rem >> 4, r = rem & 15;
    int a = (t < TP) ? pidx[t >> 10] : didx[t - TP];
    const float* A = (mat == 0) ? Aq : (mat == 1 ? Ak : Av);
    A += (size_t)a * HIDDEN * RANK + r;
    const float* xr = x + (size_t)t * HIDDEN;
    float acc = 0.f;
    for (int h = 0; h < HIDDEN; h += 4) {
        acc += xr[h] * A[(size_t)h * RANK];
        acc += xr[h + 1] * A[(size_t)(h + 1) * RANK];
        acc += xr[h + 2] * A[(size_t)(h + 2) * RANK];
        acc += xr[h + 3] * A[(size_t)(h + 3) * RANK];
    }
    T[(size_t)t * 48 + mat * 16 + r] = acc;
}

// ---------------- K2/K7: 128x128 bf16 MFMA GEMM ----------------
// C[M,N] = A[M,K] * B[K,N]. A is f32 or bf16(u16); B is f32; C is bf16(u16) or f32.
template <int A_F32, int OUT_BF16>
__global__ __launch_bounds__(256) void gemm128_kernel(const void* __restrict__ Ap,
                                                      const float* __restrict__ Bp,
                                                      void* __restrict__ Cp,
                                                      int M, int N, int K) {
    __shared__ __align__(16) u16 As[128][40];
    __shared__ __align__(16) u16 Bs[128][40];
    int tid = threadIdx.x;
    int m0 = blockIdx.y * 128, n0 = blockIdx.x * 128;
    int w = tid >> 6, lane = tid & 63, lr = lane & 15, lg = lane >> 4;
    int wr = w >> 1, wc = w & 1;
    fv4 acc[4][4] = {};
    for (int k0 = 0; k0 < K; k0 += 32) {
        __syncthreads();
        // stage A (128 rows x 32 k), convert to bf16
        {
            int r = tid >> 3, c4 = (tid & 7) * 4;
#pragma unroll
            for (int it = 0; it < 4; ++it, r += 32) {
                int row = m0 + r;
                usv4 st;
                if (A_F32) {
                    if (row < M) {
                        fv4 v = *(const fv4*)((const float*)Ap + (size_t)row * K + k0 + c4);
                        st[0] = f2b(v[0]); st[1] = f2b(v[1]); st[2] = f2b(v[2]); st[3] = f2b(v[3]);
                    } else { st[0] = 0; st[1] = 0; st[2] = 0; st[3] = 0; }
                } else {
                    if (row < M) {
                        st = *(const usv4*)((const u16*)Ap + (size_t)row * K + k0 + c4);
                    } else { st[0] = 0; st[1] = 0; st[2] = 0; st[3] = 0; }
                }
                *(usv4*)&As[r][c4] = st;
            }
        }
        // stage B transposed: Bs[n][k]
        {
            int k = tid >> 5, n4 = (tid & 31) * 4;
#pragma unroll
            for (int it = 0; it < 4; ++it, k += 8) {
                fv4 v = *(const fv4*)(Bp + (size_t)(k0 + k) * N + n0 + n4);
                Bs[n4 + 0][k] = f2b(v[0]);
                Bs[n4 + 1][k] = f2b(v[1]);
                Bs[n4 + 2][k] = f2b(v[2]);
                Bs[n4 + 3][k] = f2b(v[3]);
            }
        }
        __syncthreads();
        bf16x8 a[4], b[4];
#pragma unroll
        for (int i = 0; i < 4; ++i) {
            a[i] = *(const bf16x8*)&As[wr * 64 + i * 16 + lr][lg * 8];
            b[i] = *(const bf16x8*)&Bs[wc * 64 + i * 16 + lr][lg * 8];
        }
#pragma unroll
        for (int mi = 0; mi < 4; ++mi)
#pragma unroll
            for (int ni = 0; ni < 4; ++ni)
                acc[mi][ni] = __builtin_amdgcn_mfma_f32_16x16x32_bf16(a[mi], b[ni], acc[mi][ni], 0, 0, 0);
    }
#pragma unroll
    for (int mi = 0; mi < 4; ++mi)
#pragma unroll
        for (int ni = 0; ni < 4; ++ni) {
            int col = n0 + wc * 64 + ni * 16 + lr;
#pragma unroll
            for (int r = 0; r < 4; ++r) {
                int row = m0 + wr * 64 + mi * 16 + lg * 4 + r;
                if (row < M) {
                    if (OUT_BF16)
                        ((u16*)Cp)[(size_t)row * N + col] = f2b(acc[mi][ni][r]);
                    else
                        ((float*)Cp)[(size_t)row * N + col] = acc[mi][ni][r];
                }
            }
        }
}

// ---------------- K3: LoRA-B add + RoPE + scatter ----------------
__global__ __launch_bounds__(256) void lorab_rope_scatter_kernel(
    const u16* __restrict__ qkv, const float* __restrict__ T,
    const float* __restrict__ Bq, const float* __restrict__ Bk, const float* __restrict__ Bv,
    const int* __restrict__ pidx, const int* __restrict__ didx,
    const float* __restrict__ ctab, const float* __restrict__ stab,
    u16* __restrict__ qp, u16* __restrict__ kp, u16* __restrict__ vp,
    float* __restrict__ qd, float* __restrict__ kd, float* __restrict__ vd) {
    int t = blockIdx.x;
    __shared__ float Ts[48];
    if (threadIdx.x < 48) Ts[threadIdx.x] = T[(size_t)t * 48 + threadIdx.x];
    __syncthreads();
    bool pre = t < TP;
    int a = pre ? pidx[t >> 10] : didx[t - TP];
    int pos = pre ? (t & 1023) : L_CTX;
    int b = t >> 10;
    int td = t - TP;
    const u16* qrow = qkv + (size_t)t * QKV_DIM;
    for (int p = threadIdx.x; p < 3072; p += 256) {
        if (p < 2048) {  // Q
            int h = p >> 6, d = p & 63;
            int col = h * 128 + d;
            float v1 = b2f(qrow[col]), v2 = b2f(qrow[col + 64]);
            const float* B = Bq + (size_t)a * RANK * Q_DIM;
            float l1 = 0.f, l2 = 0.f;
#pragma unroll
            for (int r = 0; r < 16; ++r) {
                float tv = Ts[r];
                l1 += tv * B[(size_t)r * Q_DIM + col];
                l2 += tv * B[(size_t)r * Q_DIM + col + 64];
            }
            v1 += LORA_SCALE * l1; v2 += LORA_SCALE * l2;
            float c = ctab[pos * 64 + d], s = stab[pos * 64 + d];
            float o1 = v1 * c - v2 * s, o2 = v2 * c + v1 * s;
            if (pre) {
                size_t base = (((size_t)(b * 32 + h)) * 1024 + pos) * 128 + d;
                qp[base] = f2b(o1); qp[base + 64] = f2b(o2);
            } else {
                size_t base = ((size_t)(td * 32 + h)) * 128 + d;
                qd[base] = o1; qd[base + 64] = o2;
            }
        } else if (p < 2560) {  // K
            int pp = p - 2048;
            int h = pp >> 6, d = pp & 63;
            int jc = h * 128 + d;
            int col = Q_DIM + jc;
            float v1 = b2f(qrow[col]), v2 = b2f(qrow[col + 64]);
            const float* B = Bk + (size_t)a * RANK * KV_DIM;
            float l1 = 0.f, l2 = 0.f;
#pragma unroll
            for (int r = 0; r < 16; ++r) {
                float tv = Ts[16 + r];
                l1 += tv * B[(size_t)r * KV_DIM + jc];
                l2 += tv * B[(size_t)r * KV_DIM + jc + 64];
            }
            v1 += LORA_SCALE * l1; v2 += LORA_SCALE * l2;
            float c = ctab[pos * 64 + d], s = stab[pos * 64 + d];
            float o1 = v1 * c - v2 * s, o2 = v2 * c + v1 * s;
            if (pre) {
                size_t base = (((size_t)(b * 8 + h)) * 1024 + pos) * 128 + d;
                kp[base] = f2b(o1); kp[base + 64] = f2b(o2);
            } else {
                size_t base = ((size_t)(td * 8 + h)) * 128 + d;
                kd[base] = o1; kd[base + 64] = o2;
            }
        } else {  // V (no rope)
            int pp = p - 2560;
            int h = pp >> 6, d = pp & 63;
            int jc = h * 128 + d;
            int col = Q_DIM + KV_DIM + jc;
            float v1 = b2f(qrow[col]), v2 = b2f(qrow[col + 64]);
            const float* B = Bv + (size_t)a * RANK * KV_DIM;
            float l1 = 0.f, l2 = 0.f;
#pragma unroll
            for (int r = 0; r < 16; ++r) {
                float tv = Ts[32 + r];
                l1 += tv * B[(size_t)r * KV_DIM + jc];
                l2 += tv * B[(size_t)r * KV_DIM + jc + 64];
            }
            v1 += LORA_SCALE * l1; v2 += LORA_SCALE * l2;
            if (pre) {
                size_t base = (((size_t)(b * 8 + h)) * 1024 + pos) * 128 + d;
                vp[base] = f2b(v1); vp[base + 64] = f2b(v2);
            } else {
                size_t base = ((size_t)(td * 8 + h)) * 128 + d;
                vd[base] = v1; vd[base + 64] = v2;
            }
        }
    }
}

// ---------------- K4: prefill flash attention ----------------
// S^T tiles via mfma(K_tile, Q^T): lane holds col q = lane&15, rows k = (lane>>4)*4+reg.
// PV via mfma(V^T, P^T) with matching k-permutation -> O^T: row d, col q.
__global__ __launch_bounds__(256) void prefill_attn_kernel(const u16* __restrict__ qp,
                                                           const u16* __restrict__ kp,
                                                           const u16* __restrict__ vp,
                                                           u16* __restrict__ attn) {
    int qblk = blockIdx.x, h = blockIdx.y, b = blockIdx.z;
    int kvh = h >> 2;
    int tid = threadIdx.x, w = tid >> 6, lane = tid & 63, lr = lane & 15, lg = lane >> 4;
    int q0 = qblk * 64 + w * 16;
    int qc = q0 + lr;
    const u16* Q = qp + ((size_t)(b * 32 + h)) * 1024 * 128;
    const u16* K = kp + ((size_t)(b * 8 + kvh)) * 1024 * 128;
    const u16* V = vp + ((size_t)(b * 8 + kvh)) * 1024 * 128;
    bf16x8 qf[4];
#pragma unroll
    for (int dc = 0; dc < 4; ++dc)
        qf[dc] = *(const bf16x8*)(Q + (size_t)qc * 128 + dc * 32 + lg * 8);
    fv4 o[8] = {};
    float m = -INFINITY, lsum = 0.f;
    int nkb = (q0 + 47) >> 5;
    for (int kb = 0; kb < nkb; ++kb) {
        int k0 = kb * 32;
        fv4 s0 = {}, s1 = {};
#pragma unroll
        for (int dc = 0; dc < 4; ++dc) {
            bf16x8 kf0 = *(const bf16x8*)(K + (size_t)(k0 + lr) * 128 + dc * 32 + lg * 8);
            bf16x8 kf1 = *(const bf16x8*)(K + (size_t)(k0 + 16 + lr) * 128 + dc * 32 + lg * 8);
            s0 = __builtin_amdgcn_mfma_f32_16x16x32_bf16(kf0, qf[dc], s0, 0, 0, 0);
            s1 = __builtin_amdgcn_mfma_f32_16x16x32_bf16(kf1, qf[dc], s1, 0, 0, 0);
        }
        float p0[4], p1[4];
        float lm = -INFINITY;
#pragma unroll
        for (int r = 0; r < 4; ++r) {
            float x = s0[r] * SCALE;
            if (k0 + lg * 4 + r > qc) x = -INFINITY;
            p0[r] = x; lm = fmaxf(lm, x);
            x = s1[r] * SCALE;
            if (k0 + 16 + lg * 4 + r > qc) x = -INFINITY;
            p1[r] = x; lm = fmaxf(lm, x);
        }
        lm = fmaxf(lm, __shfl_xor(lm, 16));
        lm = fmaxf(lm, __shfl_xor(lm, 32));
        float mn = fmaxf(m, lm);
        float sc = __expf(m - mn);
        float rs = 0.f;
#pragma unroll
        for (int r = 0; r < 4; ++r) {
            p0[r] = __expf(p0[r] - mn);
            p1[r] = __expf(p1[r] - mn);
            rs += p0[r] + p1[r];
        }
        rs += __shfl_xor(rs, 16);
        rs += __shfl_xor(rs, 32);
        lsum = lsum * sc + rs;
        m = mn;
#pragma unroll
        for (int c = 0; c < 8; ++c) o[c] *= sc;
        bf16x8 pf;
#pragma unroll
        for (int r = 0; r < 4; ++r) {
            pf[r] = (__bf16)p0[r];
            pf[4 + r] = (__bf16)p1[r];
        }
#pragma unroll
        for (int c = 0; c < 8; ++c) {
            bf16x8 vf;
#pragma unroll
            for (int i = 0; i < 4; ++i) {
                vf[i] = __builtin_bit_cast(__bf16, V[(size_t)(k0 + lg * 4 + i) * 128 + c * 16 + lr]);
                vf[4 + i] = __builtin_bit_cast(__bf16, V[(size_t)(k0 + 16 + lg * 4 + i) * 128 + c * 16 + lr]);
            }
            o[c] = __builtin_amdgcn_mfma_f32_16x16x32_bf16(vf, pf, o[c], 0, 0, 0);
        }
    }
    float inv = 1.0f / lsum;
    size_t trow = (size_t)(b * 1024 + qc) * Q_DIM;
#pragma unroll
    for (int c = 0; c < 8; ++c)
#pragma unroll
        for (int r = 0; r < 4; ++r) {
            int feat = h * 128 + c * 16 + lg * 4 + r;
            attn[trow + feat] = f2b(o[c][r] * inv);
        }
}

// ---------------- K5: decode attention ----------------
__global__ __launch_bounds__(512) void decode_attn_kernel(const float* __restrict__ kc,
                                                          const float* __restrict__ vc,
                                                          const float* __restrict__ qd,
                                                          const float* __restrict__ kd,
                                                          const float* __restrict__ vd,
                                                          const float* __restrict__ ctab,
                                                          const float* __restrict__ stab,
                                                          u16* __restrict__ attn) {
    int blk = blockIdx.x;
    int b = blk >> 3, kvh = blk & 7;
    int tid = threadIdx.x, wv = tid >> 6, lane = tid & 63;
    float q1[4], q2[4];
#pragma unroll
    for (int g = 0; g < 4; ++g) {
        size_t qb = ((size_t)(b * 32 + kvh * 4 + g)) * 128;
        q1[g] = qd[qb + lane];
        q2[g] = qd[qb + 64 + lane];
    }
    float m[4], l[4], o1[4], o2[4];
#pragma unroll
    for (int g = 0; g < 4; ++g) { m[g] = -INFINITY; l[g] = 0.f; o1[g] = 0.f; o2[g] = 0.f; }
    for (int key = wv; key <= L_CTX; key += 8) {
        float kr1, kr2, v1, v2;
        if (key < L_CTX) {
            size_t base = (((size_t)b * L_CTX + key) * 8 + kvh) * 128;
            float k1 = kc[base + lane], k2 = kc[base + 64 + lane];
            float c = ctab[key * 64 + lane], s = stab[key * 64 + lane];
            kr1 = k1 * c - k2 * s;
            kr2 = k2 * c + k1 * s;
            v1 = vc[base + lane];
            v2 = vc[base + 64 + lane];
        } else {
            size_t base = ((size_t)(b * 8 + kvh)) * 128;
            kr1 = kd[base + lane]; kr2 = kd[base + 64 + lane];
            v1 = vd[base + lane]; v2 = vd[base + 64 + lane];
        }
#pragma unroll
        for (int g = 0; g < 4; ++g) {
            float part = q1[g] * kr1 + q2[g] * kr2;
#pragma unroll
            for (int off = 32; off; off >>= 1) part += __shfl_xor(part, off);
            float sg = part * SCALE;
            float mn = fmaxf(m[g], sg);
            float sc = __expf(m[g] - mn);
            float p = __expf(sg - mn);
            l[g] = l[g] * sc + p;
            o1[g] = o1[g] * sc + p * v1;
            o2[g] = o2[g] * sc + p * v2;
            m[g] = mn;
        }
    }
    __shared__ float lm[8][4], ll[8][4];
    __shared__ float lo[8][4][128];
#pragma unroll
    for (int g = 0; g < 4; ++g) {
        lo[wv][g][lane] = o1[g];
        lo[wv][g][64 + lane] = o2[g];
    }
    if (lane == 0)
#pragma unroll
        for (int g = 0; g < 4; ++g) { lm[wv][g] = m[g]; ll[wv][g] = l[g]; }
    __syncthreads();
    int g = tid >> 7, d = tid & 127;
    float M = -INFINITY;
#pragma unroll
    for (int wvi = 0; wvi < 8; ++wvi) M = fmaxf(M, lm[wvi][g]);
    float L = 0.f, O = 0.f;
#pragma unroll
    for (int wvi = 0; wvi < 8; ++wvi) {
        float e = __expf(lm[wvi][g] - M);
        L += ll[wvi][g] * e;
        O += lo[wvi][g][d] * e;
    }
    attn[(size_t)(TP + b) * Q_DIM + (kvh * 4 + g) * 128 + d] = f2b(O / L);
}

// ---------------- K6: LoRA-A for output ----------------
__global__ void lora_o_a_kernel(const u16* __restrict__ attn, const float* __restrict__ Ao,
                                const int* __restrict__ pidx, const int* __restrict__ didx,
                                float* __restrict__ To) {
    int gid = blockIdx.x * 256 + threadIdx.x;
    if (gid >= T_TOT * RANK) return;
    int t = gid >> 4, r = gid & 15;
    int a = (t < TP) ? pidx[t >> 10] : didx[t - TP];
    const float* A = Ao + (size_t)a * Q_DIM * RANK + r;
    const u16* xr = attn + (size_t)t * Q_DIM;
    float acc = 0.f;
    for (int j = 0; j < Q_DIM; j += 4) {
        acc += b2f(xr[j]) * A[(size_t)j * RANK];
        acc += b2f(xr[j + 1]) * A[(size_t)(j + 1) * RANK];
        acc += b2f(xr[j + 2]) * A[(size_t)(j + 2) * RANK];
        acc += b2f(xr[j + 3]) * A[(size_t)(j + 3) * RANK];
    }
    To[(size_t)t * RANK + r] = acc;
}

// ---------------- K8: final LoRA-B(O) add ----------------
__global__ void final_lora_add_kernel(float* __restrict__ out, const float* __restrict__ To,
                                      const float* __restrict__ Bo,
                                      const int* __restrict__ pidx, const int* __restrict__ didx) {
    int gid = blockIdx.x * 256 + threadIdx.x;
    if (gid >= T_TOT * HIDDEN) return;
    int t = gid >> 12, j = gid & 4095;
    int a = (t < TP) ? pidx[t >> 10] : didx[t - TP];
    const float* B = Bo + (size_t)a * RANK * HIDDEN;
    const float* Tr = To + (size_t)t * RANK;
    float acc = 0.f;
#pragma unroll
    for (int r = 0; r < 16; ++r) acc += Tr[r] * B[(size_t)r * HIDDEN + j];
    out[gid] += LORA_SCALE * acc;
}

// ---------------- launch ----------------
extern "C" void kernel_launch(void* const* d_in, const int* in_sizes, int n_in,
                              void* d_out, int out_size, void* d_ws, size_t ws_size,
                              hipStream_t stream) {
    const float* hidden = (const float*)d_in[0];
    const float* w_qkv = (const float*)d_in[1];
    const float* w_o = (const float*)d_in[2];
    const float* k_cache = (const float*)d_in[3];
    const float* v_cache = (const float*)d_in[4];
    const float* Aq = (const float*)d_in[5];
    const float* Bq = (const float*)d_in[6];
    const float* Ak = (const float*)d_in[7];
    const float* Bk = (const float*)d_in[8];
    const float* Av = (const float*)d_in[9];
    const float* Bv = (const float*)d_in[10];
    const float* Ao = (const float*)d_in[11];
    const float* Bo = (const float*)d_in[12];
    const int* pidx = (const int*)d_in[13];
    const int* didx = (const int*)d_in[14];
    float* out = (float*)d_out;

    char* ws = (char*)d_ws;
    u16* qkv = (u16*)(ws + OFF_QKV);
    u16* attn = (u16*)(ws + OFF_ATTN);
    float* T = (float*)(ws + OFF_T);
    u16* qp = (u16*)(ws + OFF_QP);
    u16* kp = (u16*)(ws + OFF_KP);
    u16* vp = (u16*)(ws + OFF_VP);
    float* qd = (float*)(ws + OFF_QD);
    float* kd = (float*)(ws + OFF_KD);
    float* vd = (float*)(ws + OFF_VD);
    float* To = (float*)(ws + OFF_TO);
    float* ctab = (float*)(ws + OFF_COS);
    float* stab = (float*)(ws + OFF_SIN);

    // K0: rope tables
    rope_tab_kernel<<<513, 256, 0, stream>>>(ctab, stab);
    // K1: lora-A ranks
    lora_a_kernel<<<(3 * T_TOT * RANK + 255) / 256, 256, 0, stream>>>(hidden, Aq, Ak, Av, pidx, didx, T);
    // K2: QKV GEMM (f32 -> bf16 out)
    gemm128_kernel<1, 1><<<dim3(QKV_DIM / 128, (T_TOT + 127) / 128), 256, 0, stream>>>(
        hidden, w_qkv, qkv, T_TOT, QKV_DIM, HIDDEN);
    // K3: lora-B add + rope + scatter
    lorab_rope_scatter_kernel<<<T_TOT, 256, 0, stream>>>(qkv, T, Bq, Bk, Bv, pidx, didx,
                                                         ctab, stab, qp, kp, vp, qd, kd, vd);
    // K4: prefill attention
    prefill_attn_kernel<<<dim3(16, 32, 4), 256, 0, stream>>>(qp, kp, vp, attn);
    // K5: decode attention
    decode_attn_kernel<<<512, 512, 0, stream>>>(k_cache, v_cache, qd, kd, vd, ctab, stab, attn);
    // K6: lora-A for O
    lora_o_a_kernel<<<(T_TOT * RANK + 255) / 256, 256, 0, stream>>>(attn, Ao, pidx, didx, To);
    // K7: O GEMM (bf16 A -> f32 out)
    gemm128_kernel<0, 0><<<dim3(HIDDEN / 128, (T_TOT + 127) / 128), 256, 0, stream>>>(
        attn, w_o, out, T_TOT, HIDDEN, Q_DIM);
    // K8: final lora add
    final_lora_add_kernel<<<(T_TOT * HIDDEN + 255) / 256, 256, 0, stream>>>(out, To, Bo, pidx, didx);
}

// Round 2
// 1841.919 us; speedup vs baseline: 1.7008x; 1.7008x over previous
//
#include <hip/hip_runtime.h>

// ---------------- constants ----------------
#define NUM_HEADS 32
#define KV_HEADS 8
#define HEAD_DIM 128
#define HIDDEN 4096
#define Q_DIM 4096
#define KV_DIM 1024
#define QKV_DIM 6144
#define GROUP 4
#define BP 4
#define S_LEN 1024
#define BD 64
#define L_CTX 2048
#define RANK 16
#define NA 8
#define TP (BP * S_LEN)      // 4096
#define T_TOT (TP + BD)      // 4160
#define M_PAD 4224           // T_TOT padded to 128 multiple
#define SCALE 0.08838834764831845f
#define LORA_SCALE 0.5f

typedef float fv4 __attribute__((ext_vector_type(4)));
typedef __bf16 bf16x8 __attribute__((ext_vector_type(8)));
typedef unsigned short usv4 __attribute__((ext_vector_type(4)));
typedef unsigned short u16;

__device__ __forceinline__ float b2f(u16 u) {
    unsigned int x = ((unsigned int)u) << 16;
    return __builtin_bit_cast(float, x);
}
__device__ __forceinline__ u16 f2b(float f) {
    unsigned int u = __builtin_bit_cast(unsigned int, f);
    unsigned int r = u + 0x7fffu + ((u >> 16) & 1u);
    return (u16)(r >> 16);
}
__device__ __forceinline__ void gload_lds16(const void* g, void* l) {
    __builtin_amdgcn_global_load_lds((const __attribute__((address_space(1))) void*)g,
                                     (__attribute__((address_space(3))) void*)l, 16, 0, 0);
}

// ---------------- workspace layout (bytes) ----------------
// region liveness:
//   qkv (K2 out) -> read K3; attn alias (K4/K5 out) -> read K6,K7
//   hidden_bf16 (conv out, K2 in) -> dead after K2 -> qp (K3 out, K4 in) -> dead after K4 -> woT (Kt2 out, K7 in)
//   wqkvT (Kt1 out, K2 in) -> dead after K2 -> kp,vp,qd,kd,vd (K3 out)
#define OFF_QKV  ((size_t)0)                  // 4224*6144*2 = 51,904,512 ; attn alias [4224][4096] bf16
#define OFF_ATTN OFF_QKV
#define OFF_HB   ((size_t)51904512)           // hidden bf16 [4224][4096] = 34,603,008
#define OFF_QP   OFF_HB                       // (4,32,1024,128) bf16 = 33,554,432
#define OFF_WOT  OFF_HB                       // woT bf16 [4096][4096] = 33,554,432
#define OFF_WQT  ((size_t)86507520)           // wqkvT bf16 [6144][4096] = 50,331,648
#define OFF_KP   ((size_t)86507520)           // (4,8,1024,128) bf16 = 8,388,608
#define OFF_VP   ((size_t)94896128)           // 8,388,608
#define OFF_QD   ((size_t)103284736)          // (64,32,128) f32 = 1,048,576
#define OFF_KD   ((size_t)104333312)          // 262,144
#define OFF_VD   ((size_t)104595456)          // 262,144
#define OFF_T    ((size_t)136839168)          // 4160*48*4 = 798,720
#define OFF_TO   ((size_t)137637888)          // 4160*16*4 = 266,240
#define OFF_COS  ((size_t)137904128)          // 2049*64*4 = 524,544
#define OFF_SIN  ((size_t)138428672)          // 524,544  -> total 138,953,216

// ---------------- K0: rope tables ----------------
__global__ void rope_tab_kernel(float* ctab, float* stab) {
    int idx = blockIdx.x * 256 + threadIdx.x;
    if (idx >= 2049 * 64) return;
    int pos = idx >> 6, d = idx & 63;
    float inv = 1.0f / powf(10000.0f, (float)d / 64.0f);
    float f = (float)pos * inv;
    ctab[idx] = cosf(f);
    stab[idx] = sinf(f);
}

// ---------------- Kc: hidden f32 -> bf16 (padded rows zeroed) ----------------
__global__ void conv_hidden_kernel(const float* __restrict__ x, u16* __restrict__ y) {
    int gid = blockIdx.x * 256 + threadIdx.x;
    if (gid >= M_PAD * (HIDDEN / 8)) return;
    size_t base = (size_t)gid * 8;
    int row = gid >> 9;  // 512 groups of 8 per row
    usv4 lo, hi;
    if (row < T_TOT) {
        fv4 a = *(const fv4*)(x + base);
        fv4 b = *(const fv4*)(x + base + 4);
        lo[0] = f2b(a[0]); lo[1] = f2b(a[1]); lo[2] = f2b(a[2]); lo[3] = f2b(a[3]);
        hi[0] = f2b(b[0]); hi[1] = f2b(b[1]); hi[2] = f2b(b[2]); hi[3] = f2b(b[3]);
    } else {
        lo[0] = 0; lo[1] = 0; lo[2] = 0; lo[3] = 0;
        hi[0] = 0; hi[1] = 0; hi[2] = 0; hi[3] = 0;
    }
    *(usv4*)(y + base) = lo;
    *(usv4*)(y + base + 4) = hi;
}

// ---------------- Kt: transpose f32 [R][C] -> bf16 [C][R] ----------------
__global__ __launch_bounds__(256) void transpose_f32_bf16_kernel(const float* __restrict__ in,
                                                                 u16* __restrict__ out,
                                                                 int R, int C) {
    __shared__ float tile[64][65];
    int r0 = blockIdx.y * 64, c0 = blockIdx.x * 64;
    int t = threadIdx.x;
    int tr = t >> 4, tc4 = (t & 15) * 4;
#pragma unroll
    for (int it = 0; it < 4; ++it) {
        int r = tr + it * 16;
        fv4 v = *(const fv4*)(in + (size_t)(r0 + r) * C + c0 + tc4);
        tile[r][tc4 + 0] = v[0]; tile[r][tc4 + 1] = v[1];
        tile[r][tc4 + 2] = v[2]; tile[r][tc4 + 3] = v[3];
    }
    __syncthreads();
#pragma unroll
    for (int it = 0; it < 4; ++it) {
        int c = tr + it * 16;
        usv4 st;
        st[0] = f2b(tile[tc4 + 0][c]); st[1] = f2b(tile[tc4 + 1][c]);
        st[2] = f2b(tile[tc4 + 2][c]); st[3] = f2b(tile[tc4 + 3][c]);
        *(usv4*)(out + (size_t)(c0 + c) * R + r0 + tc4) = st;
    }
}

// ---------------- K1: LoRA-A ranks (q,k,v) ----------------
__global__ void lora_a_kernel(const float* __restrict__ x,
                              const float* __restrict__ Aq, const float* __restrict__ Ak,
                              const float* __restrict__ Av,
                              const int* __restrict__ pidx, const int* __restrict__ didx,
                              float* __restrict__ T) {
    int gid = blockIdx.x * 256 + threadIdx.x;
    const int per_mat = T_TOT * RANK;
    if (gid >= 3 * per_mat) return;
    int mat = gid / per_mat;
    int rem = gid - mat * per_mat;
    int t = rem >> 4, r = rem & 15;
    int a = (t < TP) ? pidx[t >> 10] : didx[t - TP];
    const float* A = (mat == 0) ? Aq : (mat == 1 ? Ak : Av);
    A += (size_t)a * HIDDEN * RANK + r;
    const float* xr = x + (size_t)t * HIDDEN;
    float acc = 0.f;
    for (int h = 0; h < HIDDEN; h += 4) {
        acc += xr[h] * A[(size_t)h * RANK];
        acc += xr[h + 1] * A[(size_t)(h + 1) * RANK];
        acc += xr[h + 2] * A[(size_t)(h + 2) * RANK];
        acc += xr[h + 3] * A[(size_t)(h + 3) * RANK];
    }
    T[(size_t)t * 48 + mat * 16 + r] = acc;
}

// ---------------- K2/K7: m97-structure bf16 GEMM (A[M][K] x BT[N][K]) ----------------
// 128x128 tile, BK=32, 4 waves, global_load_lds width-16 linear LDS staging.
template <int OUT_BF16>
__global__ __launch_bounds__(256) void gemm_bt_kernel(const u16* __restrict__ A,
                                                      const u16* __restrict__ BT,
                                                      void* __restrict__ Cp,
                                                      int Mstore, int N, int K) {
    __shared__ __align__(16) u16 As[128 * 32];
    __shared__ __align__(16) u16 Bs[128 * 32];
    int tid = threadIdx.x;
    int m0 = blockIdx.y * 128, n0 = blockIdx.x * 128;
    int lane = tid & 63, w = tid >> 6, lr = lane & 15, lg = lane >> 4;
    int wr = w >> 1, wc = w & 1;
    // staging decomposition: per call j (j=0,1) covers 64 rows; lane i of wave w
    // lands at LDS byte (j*4096 + w*1024 + i*16) == row (j*64 + tid/4) col (tid%4)*8 u16
    int arow = tid >> 2;
    int acol = (tid & 3) * 8;
    const u16* Abase = A + (size_t)(m0 + arow) * K + acol;
    const u16* Bbase = BT + (size_t)(n0 + arow) * K + acol;
    char* AsB = (char*)As + w * 1024;
    char* BsB = (char*)Bs + w * 1024;
    fv4 acc[4][4] = {};
    for (int k0 = 0; k0 < K; k0 += 32) {
#pragma unroll
        for (int j = 0; j < 2; ++j) {
            gload_lds16(Abase + (size_t)j * 64 * K + k0, AsB + j * 4096);
            gload_lds16(Bbase + (size_t)j * 64 * K + k0, BsB + j * 4096);
        }
        __syncthreads();
        bf16x8 af[4], bf[4];
#pragma unroll
        for (int i = 0; i < 4; ++i) {
            af[i] = *(const bf16x8*)&As[(wr * 64 + i * 16 + lr) * 32 + lg * 8];
            bf[i] = *(const bf16x8*)&Bs[(wc * 64 + i * 16 + lr) * 32 + lg * 8];
        }
#pragma unroll
        for (int mi = 0; mi < 4; ++mi)
#pragma unroll
            for (int ni = 0; ni < 4; ++ni)
                acc[mi][ni] = __builtin_amdgcn_mfma_f32_16x16x32_bf16(af[mi], bf[ni], acc[mi][ni], 0, 0, 0);
        __syncthreads();
    }
#pragma unroll
    for (int mi = 0; mi < 4; ++mi)
#pragma unroll
        for (int ni = 0; ni < 4; ++ni) {
            int col = n0 + wc * 64 + ni * 16 + lr;
#pragma unroll
            for (int r = 0; r < 4; ++r) {
                int row = m0 + wr * 64 + mi * 16 + lg * 4 + r;
                if (row < Mstore) {
                    if (OUT_BF16)
                        ((u16*)Cp)[(size_t)row * N + col] = f2b(acc[mi][ni][r]);
                    else
                        ((float*)Cp)[(size_t)row * N + col] = acc[mi][ni][r];
                }
            }
        }
}

// ---------------- K3: LoRA-B add + RoPE + scatter ----------------
__global__ __launch_bounds__(256) void lorab_rope_scatter_kernel(
    const u16* __restrict__ qkv, const float* __restrict__ T,
    const float* __restrict__ Bq, const float* __restrict__ Bk, const float* __restrict__ Bv,
    const int* __restrict__ pidx, const int* __restrict__ didx,
    const float* __restrict__ ctab, const float* __restrict__ stab,
    u16* __restrict__ qp, u16* __restrict__ kp, u16* __restrict__ vp,
    float* __restrict__ qd, float* __restrict__ kd, float* __restrict__ vd) {
    int t = blockIdx.x;
    __shared__ float Ts[48];
    if (threadIdx.x < 48) Ts[threadIdx.x] = T[(size_t)t * 48 + threadIdx.x];
    __syncthreads();
    bool pre = t < TP;
    int a = pre ? pidx[t >> 10] : didx[t - TP];
    int pos = pre ? (t & 1023) : L_CTX;
    int b = t >> 10;
    int td = t - TP;
    const u16* qrow = qkv + (size_t)t * QKV_DIM;
    for (int p = threadIdx.x; p < 3072; p += 256) {
        if (p < 2048) {  // Q
            int h = p >> 6, d = p & 63;
            int col = h * 128 + d;
            float v1 = b2f(qrow[col]), v2 = b2f(qrow[col + 64]);
            const float* B = Bq + (size_t)a * RANK * Q_DIM;
            float l1 = 0.f, l2 = 0.f;
#pragma unroll
            for (int r = 0; r < 16; ++r) {
                float tv = Ts[r];
                l1 += tv * B[(size_t)r * Q_DIM + col];
                l2 += tv * B[(size_t)r * Q_DIM + col + 64];
            }
            v1 += LORA_SCALE * l1; v2 += LORA_SCALE * l2;
            float c = ctab[pos * 64 + d], s = stab[pos * 64 + d];
            float o1 = v1 * c - v2 * s, o2 = v2 * c + v1 * s;
            if (pre) {
                size_t base = (((size_t)(b * 32 + h)) * 1024 + pos) * 128 + d;
                qp[base] = f2b(o1); qp[base + 64] = f2b(o2);
            } else {
                size_t base = ((size_t)(td * 32 + h)) * 128 + d;
                qd[base] = o1; qd[base + 64] = o2;
            }
        } else if (p < 2560) {  // K
            int pp = p - 2048;
            int h = pp >> 6, d = pp & 63;
            int jc = h * 128 + d;
            int col = Q_DIM + jc;
            float v1 = b2f(qrow[col]), v2 = b2f(qrow[col + 64]);
            const float* B = Bk + (size_t)a * RANK * KV_DIM;
            float l1 = 0.f, l2 = 0.f;
#pragma unroll
            for (int r = 0; r < 16; ++r) {
                float tv = Ts[16 + r];
                l1 += tv * B[(size_t)r * KV_DIM + jc];
                l2 += tv * B[(size_t)r * KV_DIM + jc + 64];
            }
            v1 += LORA_SCALE * l1; v2 += LORA_SCALE * l2;
            float c = ctab[pos * 64 + d], s = stab[pos * 64 + d];
            float o1 = v1 * c - v2 * s, o2 = v2 * c + v1 * s;
            if (pre) {
                size_t base = (((size_t)(b * 8 + h)) * 1024 + pos) * 128 + d;
                kp[base] = f2b(o1); kp[base + 64] = f2b(o2);
            } else {
                size_t base = ((size_t)(td * 8 + h)) * 128 + d;
                kd[base] = o1; kd[base + 64] = o2;
            }
        } else {  // V (no rope)
            int pp = p - 2560;
            int h = pp >> 6, d = pp & 63;
            int jc = h * 128 + d;
            int col = Q_DIM + KV_DIM + jc;
            float v1 = b2f(qrow[col]), v2 = b2f(qrow[col + 64]);
            const float* B = Bv + (size_t)a * RANK * KV_DIM;
            float l1 = 0.f, l2 = 0.f;
#pragma unroll
            for (int r = 0; r < 16; ++r) {
                float tv = Ts[32 + r];
                l1 += tv * B[(size_t)r * KV_DIM + jc];
                l2 += tv * B[(size_t)r * KV_DIM + jc + 64];
            }
            v1 += LORA_SCALE * l1; v2 += LORA_SCALE * l2;
            if (pre) {
                size_t base = (((size_t)(b * 8 + h)) * 1024 + pos) * 128 + d;
                vp[base] = f2b(v1); vp[base + 64] = f2b(v2);
            } else {
                size_t base = ((size_t)(td * 8 + h)) * 128 + d;
                vd[base] = v1; vd[base + 64] = v2;
            }
        }
    }
}

// ---------------- K4: prefill flash attention ----------------
__global__ __launch_bounds__(256) void prefill_attn_kernel(const u16* __restrict__ qp,
                                                           const u16* __restrict__ kp,
                                                           const u16* __restrict__ vp,
                                                           u16* __restrict__ attn) {
    int qblk = blockIdx.x, h = blockIdx.y, b = blockIdx.z;
    int kvh = h >> 2;
    int tid = threadIdx.x, w = tid >> 6, lane = tid & 63, lr = lane & 15, lg = lane >> 4;
    int q0 = qblk * 64 + w * 16;
    int qc = q0 + lr;
    const u16* Q = qp + ((size_t)(b * 32 + h)) * 1024 * 128;
    const u16* K = kp + ((size_t)(b * 8 + kvh)) * 1024 * 128;
    const u16* V = vp + ((size_t)(b * 8 + kvh)) * 1024 * 128;
    bf16x8 qf[4];
#pragma unroll
    for (int dc = 0; dc < 4; ++dc)
        qf[dc] = *(const bf16x8*)(Q + (size_t)qc * 128 + dc * 32 + lg * 8);
    fv4 o[8] = {};
    float m = -INFINITY, lsum = 0.f;
    int nkb = (q0 + 47) >> 5;
    for (int kb = 0; kb < nkb; ++kb) {
        int k0 = kb * 32;
        fv4 s0 = {}, s1 = {};
#pragma unroll
        for (int dc = 0; dc < 4; ++dc) {
            bf16x8 kf0 = *(const bf16x8*)(K + (size_t)(k0 + lr) * 128 + dc * 32 + lg * 8);
            bf16x8 kf1 = *(const bf16x8*)(K + (size_t)(k0 + 16 + lr) * 128 + dc * 32 + lg * 8);
            s0 = __builtin_amdgcn_mfma_f32_16x16x32_bf16(kf0, qf[dc], s0, 0, 0, 0);
            s1 = __builtin_amdgcn_mfma_f32_16x16x32_bf16(kf1, qf[dc], s1, 0, 0, 0);
        }
        float p0[4], p1[4];
        float lm = -INFINITY;
#pragma unroll
        for (int r = 0; r < 4; ++r) {
            float x = s0[r] * SCALE;
            if (k0 + lg * 4 + r > qc) x = -INFINITY;
            p0[r] = x; lm = fmaxf(lm, x);
            x = s1[r] * SCALE;
            if (k0 + 16 + lg * 4 + r > qc) x = -INFINITY;
            p1[r] = x; lm = fmaxf(lm, x);
        }
        lm = fmaxf(lm, __shfl_xor(lm, 16));
        lm = fmaxf(lm, __shfl_xor(lm, 32));
        float mn = fmaxf(m, lm);
        float sc = __expf(m - mn);
        float rs = 0.f;
#pragma unroll
        for (int r = 0; r < 4; ++r) {
            p0[r] = __expf(p0[r] - mn);
            p1[r] = __expf(p1[r] - mn);
            rs += p0[r] + p1[r];
        }
        rs += __shfl_xor(rs, 16);
        rs += __shfl_xor(rs, 32);
        lsum = lsum * sc + rs;
        m = mn;
#pragma unroll
        for (int c = 0; c < 8; ++c) o[c] *= sc;
        bf16x8 pf;
#pragma unroll
        for (int r = 0; r < 4; ++r) {
            pf[r] = (__bf16)p0[r];
            pf[4 + r] = (__bf16)p1[r];
        }
#pragma unroll
        for (int c = 0; c < 8; ++c) {
            bf16x8 vf;
#pragma unroll
            for (int i = 0; i < 4; ++i) {
                vf[i] = __builtin_bit_cast(__bf16, V[(size_t)(k0 + lg * 4 + i) * 128 + c * 16 + lr]);
                vf[4 + i] = __builtin_bit_cast(__bf16, V[(size_t)(k0 + 16 + lg * 4 + i) * 128 + c * 16 + lr]);
            }
            o[c] = __builtin_amdgcn_mfma_f32_16x16x32_bf16(vf, pf, o[c], 0, 0, 0);
        }
    }
    float inv = 1.0f / lsum;
    size_t trow = (size_t)(b * 1024 + qc) * Q_DIM;
#pragma unroll
    for (int c = 0; c < 8; ++c)
#pragma unroll
        for (int r = 0; r < 4; ++r) {
            int feat = h * 128 + c * 16 + lg * 4 + r;
            attn[trow + feat] = f2b(o[c][r] * inv);
        }
}

// ---------------- K5: decode attention ----------------
__global__ __launch_bounds__(512) void decode_attn_kernel(const float* __restrict__ kc,
                                                          const float* __restrict__ vc,
                                                          const float* __restrict__ qd,
                                                          const float* __restrict__ kd,
                                                          const float* __restrict__ vd,
                                                          const float* __restrict__ ctab,
                                                          const float* __restrict__ stab,
                                                          u16* __restrict__ attn) {
    int blk = blockIdx.x;
    int b = blk >> 3, kvh = blk & 7;
    int tid = threadIdx.x, wv = tid >> 6, lane = tid & 63;
    float q1[4], q2[4];
#pragma unroll
    for (int g = 0; g < 4; ++g) {
        size_t qb = ((size_t)(b * 32 + kvh * 4 + g)) * 128;
        q1[g] = qd[qb + lane];
        q2[g] = qd[qb + 64 + lane];
    }
    float m[4], l[4], o1[4], o2[4];
#pragma unroll
    for (int g = 0; g < 4; ++g) { m[g] = -INFINITY; l[g] = 0.f; o1[g] = 0.f; o2[g] = 0.f; }
    for (int key = wv; key <= L_CTX; key += 8) {
        float kr1, kr2, v1, v2;
        if (key < L_CTX) {
            size_t base = (((size_t)b * L_CTX + key) * 8 + kvh) * 128;
            float k1 = kc[base + lane], k2 = kc[base + 64 + lane];
            float c = ctab[key * 64 + lane], s = stab[key * 64 + lane];
            kr1 = k1 * c - k2 * s;
            kr2 = k2 * c + k1 * s;
            v1 = vc[base + lane];
            v2 = vc[base + 64 + lane];
        } else {
            size_t base = ((size_t)(b * 8 + kvh)) * 128;
            kr1 = kd[base + lane]; kr2 = kd[base + 64 + lane];
            v1 = vd[base + lane]; v2 = vd[base + 64 + lane];
        }
#pragma unroll
        for (int g = 0; g < 4; ++g) {
            float part = q1[g] * kr1 + q2[g] * kr2;
#pragma unroll
            for (int off = 32; off; off >>= 1) part += __shfl_xor(part, off);
            float sg = part * SCALE;
            float mn = fmaxf(m[g], sg);
            float sc = __expf(m[g] - mn);
            float p = __expf(sg - mn);
            l[g] = l[g] * sc + p;
            o1[g] = o1[g] * sc + p * v1;
            o2[g] = o2[g] * sc + p * v2;
            m[g] = mn;
        }
    }
    __shared__ float lm[8][4], ll[8][4];
    __shared__ float lo[8][4][128];
#pragma unroll
    for (int g = 0; g < 4; ++g) {
        lo[wv][g][lane] = o1[g];
        lo[wv][g][64 + lane] = o2[g];
    }
    if (lane == 0)
#pragma unroll
        for (int g = 0; g < 4; ++g) { lm[wv][g] = m[g]; ll[wv][g] = l[g]; }
    __syncthreads();
    int g = tid >> 7, d = tid & 127;
    float M = -INFINITY;
#pragma unroll
    for (int wvi = 0; wvi < 8; ++wvi) M = fmaxf(M, lm[wvi][g]);
    float L = 0.f, O = 0.f;
#pragma unroll
    for (int wvi = 0; wvi < 8; ++wvi) {
        float e = __expf(lm[wvi][g] - M);
        L += ll[wvi][g] * e;
        O += lo[wvi][g][d] * e;
    }
    attn[(size_t)(TP + b) * Q_DIM + (kvh * 4 + g) * 128 + d] = f2b(O / L);
}

// ---------------- K6: LoRA-A for output ----------------
__global__ void lora_o_a_kernel(const u16* __restrict__ attn, const float* __restrict__ Ao,
                                const int* __restrict__ pidx, const int* __restrict__ didx,
                                float* __restrict__ To) {
    int gid = blockIdx.x * 256 + threadIdx.x;
    if (gid >= T_TOT * RANK) return;
    int t = gid >> 4, r = gid & 15;
    int a = (t < TP) ? pidx[t >> 10] : didx[t - TP];
    const float* A = Ao + (size_t)a * Q_DIM * RANK + r;
    const u16* xr = attn + (size_t)t * Q_DIM;
    float acc = 0.f;
    for (int j = 0; j < Q_DIM; j += 4) {
        acc += b2f(xr[j]) * A[(size_t)j * RANK];
        acc += b2f(xr[j + 1]) * A[(size_t)(j + 1) * RANK];
        acc += b2f(xr[j + 2]) * A[(size_t)(j + 2) * RANK];
        acc += b2f(xr[j + 3]) * A[(size_t)(j + 3) * RANK];
    }
    To[(size_t)t * RANK + r] = acc;
}

// ---------------- K8: final LoRA-B(O) add ----------------
__global__ void final_lora_add_kernel(float* __restrict__ out, const float* __restrict__ To,
                                      const float* __restrict__ Bo,
                                      const int* __restrict__ pidx, const int* __restrict__ didx) {
    int gid = blockIdx.x * 256 + threadIdx.x;
    if (gid >= T_TOT * HIDDEN) return;
    int t = gid >> 12, j = gid & 4095;
    int a = (t < TP) ? pidx[t >> 10] : didx[t - TP];
    const float* B = Bo + (size_t)a * RANK * HIDDEN;
    const float* Tr = To + (size_t)t * RANK;
    float acc = 0.f;
#pragma unroll
    for (int r = 0; r < 16; ++r) acc += Tr[r] * B[(size_t)r * HIDDEN + j];
    out[gid] += LORA_SCALE * acc;
}

// ---------------- launch ----------------
extern "C" void kernel_launch(void* const* d_in, const int* in_sizes, int n_in,
                              void* d_out, int out_size, void* d_ws, size_t ws_size,
                              hipStream_t stream) {
    const float* hidden = (const float*)d_in[0];
    const float* w_qkv = (const float*)d_in[1];
    const float* w_o = (const float*)d_in[2];
    const float* k_cache = (const float*)d_in[3];
    const float* v_cache = (const float*)d_in[4];
    const float* Aq = (const float*)d_in[5];
    const float* Bq = (const float*)d_in[6];
    const float* Ak = (const float*)d_in[7];
    const float* Bk = (const float*)d_in[8];
    const float* Av = (const float*)d_in[9];
    const float* Bv = (const float*)d_in[10];
    const float* Ao = (const float*)d_in[11];
    const float* Bo = (const float*)d_in[12];
    const int* pidx = (const int*)d_in[13];
    const int* didx = (const int*)d_in[14];
    float* out = (float*)d_out;

    char* ws = (char*)d_ws;
    u16* qkv = (u16*)(ws + OFF_QKV);
    u16* attn = (u16*)(ws + OFF_ATTN);
    u16* hb = (u16*)(ws + OFF_HB);
    u16* wqT = (u16*)(ws + OFF_WQT);
    u16* woT = (u16*)(ws + OFF_WOT);
    float* T = (float*)(ws + OFF_T);
    u16* qp = (u16*)(ws + OFF_QP);
    u16* kp = (u16*)(ws + OFF_KP);
    u16* vp = (u16*)(ws + OFF_VP);
    float* qd = (float*)(ws + OFF_QD);
    float* kd = (float*)(ws + OFF_KD);
    float* vd = (float*)(ws + OFF_VD);
    float* To = (float*)(ws + OFF_TO);
    float* ctab = (float*)(ws + OFF_COS);
    float* stab = (float*)(ws + OFF_SIN);

    // K0: rope tables
    rope_tab_kernel<<<513, 256, 0, stream>>>(ctab, stab);
    // Kc: hidden f32 -> bf16 (padded)
    conv_hidden_kernel<<<(M_PAD * (HIDDEN / 8) + 255) / 256, 256, 0, stream>>>(hidden, hb);
    // Kt1: w_qkv [4096][6144] -> wqkvT bf16 [6144][4096]
    transpose_f32_bf16_kernel<<<dim3(QKV_DIM / 64, HIDDEN / 64), 256, 0, stream>>>(w_qkv, wqT, HIDDEN, QKV_DIM);
    // K1: lora-A ranks
    lora_a_kernel<<<(3 * T_TOT * RANK + 255) / 256, 256, 0, stream>>>(hidden, Aq, Ak, Av, pidx, didx, T);
    // K2: QKV GEMM (bf16 x bf16^T -> bf16), padded M
    gemm_bt_kernel<1><<<dim3(QKV_DIM / 128, M_PAD / 128), 256, 0, stream>>>(
        hb, wqT, qkv, M_PAD, QKV_DIM, HIDDEN);
    // K3: lora-B add + rope + scatter (overwrites hb region with qp; wqT region with kp/vp/qd/kd/vd)
    lorab_rope_scatter_kernel<<<T_TOT, 256, 0, stream>>>(qkv, T, Bq, Bk, Bv, pidx, didx,
                                                         ctab, stab, qp, kp, vp, qd, kd, vd);
    // K4: prefill attention
    prefill_attn_kernel<<<dim3(16, 32, 4), 256, 0, stream>>>(qp, kp, vp, attn);
    // K5: decode attention
    decode_attn_kernel<<<512, 512, 0, stream>>>(k_cache, v_cache, qd, kd, vd, ctab, stab, attn);
    // Kt2: w_o [4096][4096] -> woT bf16 (overwrites qp region; qp dead after K4)
    transpose_f32_bf16_kernel<<<dim3(HIDDEN / 64, Q_DIM / 64), 256, 0, stream>>>(w_o, woT, Q_DIM, HIDDEN);
    // K6: lora-A for O
    lora_o_a_kernel<<<(T_TOT * RANK + 255) / 256, 256, 0, stream>>>(attn, Ao, pidx, didx, To);
    // K7: O GEMM (bf16 x bf16^T -> f32), guard rows at T_TOT
    gemm_bt_kernel<0><<<dim3(HIDDEN / 128, M_PAD / 128), 256, 0, stream>>>(
        attn, woT, out, T_TOT, HIDDEN, Q_DIM);
    // K8: final lora add
    final_lora_add_kernel<<<(T_TOT * HIDDEN + 255) / 256, 256, 0, stream>>>(out, To, Bo, pidx, didx);
}

// Round 7
// 1767.508 us; speedup vs baseline: 1.7724x; 1.0421x over previous
//
#include <hip/hip_runtime.h>

// ---------------- constants ----------------
#define NUM_HEADS 32
#define KV_HEADS 8
#define HEAD_DIM 128
#define HIDDEN 4096
#define Q_DIM 4096
#define KV_DIM 1024
#define QKV_DIM 6144
#define GROUP 4
#define BP 4
#define S_LEN 1024
#define BD 64
#define L_CTX 2048
#define RANK 16
#define NA 8
#define TP (BP * S_LEN)      // 4096
#define T_TOT (TP + BD)      // 4160
#define M_PAD 4224           // T_TOT padded to 128 multiple
#define SCALE 0.08838834764831845f
#define LORA_SCALE 0.5f

typedef float fv4 __attribute__((ext_vector_type(4)));
typedef __bf16 bf16x8 __attribute__((ext_vector_type(8)));
typedef unsigned short usv4 __attribute__((ext_vector_type(4)));
typedef unsigned short u16;

__device__ __forceinline__ float b2f(u16 u) {
    unsigned int x = ((unsigned int)u) << 16;
    return __builtin_bit_cast(float, x);
}
__device__ __forceinline__ u16 f2b(float f) {
    unsigned int u = __builtin_bit_cast(unsigned int, f);
    unsigned int r = u + 0x7fffu + ((u >> 16) & 1u);
    return (u16)(r >> 16);
}
__device__ __forceinline__ void gload_lds16(const void* g, void* l) {
    __builtin_amdgcn_global_load_lds((const __attribute__((address_space(1))) void*)g,
                                     (__attribute__((address_space(3))) void*)l, 16, 0, 0);
}

// ---------------- workspace layout (bytes) — EXACT round-2 passing layout ----------------
#define OFF_QKV  ((size_t)0)                  // [4224][6144] bf16 ; attn alias [4224][4096] bf16
#define OFF_ATTN OFF_QKV
#define OFF_HB   ((size_t)51904512)           // hidden bf16 [4224][4096] (alias qp, then woT)
#define OFF_QP   OFF_HB
#define OFF_WOT  OFF_HB
#define OFF_WQT  ((size_t)86507520)           // wqkvT bf16 [6144][4096] (alias kp/vp/qd/kd/vd after K2)
#define OFF_KP   ((size_t)86507520)
#define OFF_VP   ((size_t)94896128)
#define OFF_QD   ((size_t)103284736)
#define OFF_KD   ((size_t)104333312)
#define OFF_VD   ((size_t)104595456)
#define OFF_T    ((size_t)136839168)          // T [4160][48] f32
#define OFF_TO   ((size_t)137637888)          // To [4160][16] f32
#define OFF_COS  ((size_t)137904128)
#define OFF_SIN  ((size_t)138428672)          // total 138,953,216 (proven bound)

// ---------------- K0: rope tables ----------------
__global__ void rope_tab_kernel(float* ctab, float* stab) {
    int idx = blockIdx.x * 256 + threadIdx.x;
    if (idx >= 2049 * 64) return;
    int pos = idx >> 6, d = idx & 63;
    float inv = 1.0f / powf(10000.0f, (float)d / 64.0f);
    float f = (float)pos * inv;
    ctab[idx] = cosf(f);
    stab[idx] = sinf(f);
}

// ---------------- Kc: hidden f32 -> bf16 (padded rows zeroed) ----------------
__global__ void conv_hidden_kernel(const float* __restrict__ x, u16* __restrict__ y) {
    int gid = blockIdx.x * 256 + threadIdx.x;
    if (gid >= M_PAD * (HIDDEN / 8)) return;
    size_t base = (size_t)gid * 8;
    int row = gid >> 9;
    usv4 lo, hi;
    if (row < T_TOT) {
        fv4 a = *(const fv4*)(x + base);
        fv4 b = *(const fv4*)(x + base + 4);
        lo[0] = f2b(a[0]); lo[1] = f2b(a[1]); lo[2] = f2b(a[2]); lo[3] = f2b(a[3]);
        hi[0] = f2b(b[0]); hi[1] = f2b(b[1]); hi[2] = f2b(b[2]); hi[3] = f2b(b[3]);
    } else {
        lo[0] = 0; lo[1] = 0; lo[2] = 0; lo[3] = 0;
        hi[0] = 0; hi[1] = 0; hi[2] = 0; hi[3] = 0;
    }
    *(usv4*)(y + base) = lo;
    *(usv4*)(y + base + 4) = hi;
}

// ---------------- Kt: transpose f32 [R][C] -> bf16 [C][R] ----------------
__global__ __launch_bounds__(256) void transpose_f32_bf16_kernel(const float* __restrict__ in,
                                                                 u16* __restrict__ out,
                                                                 int R, int C) {
    __shared__ float tile[64][65];
    int r0 = blockIdx.y * 64, c0 = blockIdx.x * 64;
    int t = threadIdx.x;
    int tr = t >> 4, tc4 = (t & 15) * 4;
#pragma unroll
    for (int it = 0; it < 4; ++it) {
        int r = tr + it * 16;
        fv4 v = *(const fv4*)(in + (size_t)(r0 + r) * C + c0 + tc4);
        tile[r][tc4 + 0] = v[0]; tile[r][tc4 + 1] = v[1];
        tile[r][tc4 + 2] = v[2]; tile[r][tc4 + 3] = v[3];
    }
    __syncthreads();
#pragma unroll
    for (int it = 0; it < 4; ++it) {
        int c = tr + it * 16;
        usv4 st;
        st[0] = f2b(tile[tc4 + 0][c]); st[1] = f2b(tile[tc4 + 1][c]);
        st[2] = f2b(tile[tc4 + 2][c]); st[3] = f2b(tile[tc4 + 3][c]);
        *(usv4*)(out + (size_t)(c0 + c) * R + r0 + tc4) = st;
    }
}

// ---------------- K1: LoRA-A ranks (q,k,v) — round-2 scalar version ----------------
__global__ void lora_a_kernel(const float* __restrict__ x,
                              const float* __restrict__ Aq, const float* __restrict__ Ak,
                              const float* __restrict__ Av,
                              const int* __restrict__ pidx, const int* __restrict__ didx,
                              float* __restrict__ T) {
    int gid = blockIdx.x * 256 + threadIdx.x;
    const int per_mat = T_TOT * RANK;
    if (gid >= 3 * per_mat) return;
    int mat = gid / per_mat;
    int rem = gid - mat * per_mat;
    int t = rem >> 4, r = rem & 15;
    int a = (t < TP) ? pidx[t >> 10] : didx[t - TP];
    const float* A = (mat == 0) ? Aq : (mat == 1 ? Ak : Av);
    A += (size_t)a * HIDDEN * RANK + r;
    const float* xr = x + (size_t)t * HIDDEN;
    float acc = 0.f;
    for (int h = 0; h < HIDDEN; h += 4) {
        acc += xr[h] * A[(size_t)h * RANK];
        acc += xr[h + 1] * A[(size_t)(h + 1) * RANK];
        acc += xr[h + 2] * A[(size_t)(h + 2) * RANK];
        acc += xr[h + 3] * A[(size_t)(h + 3) * RANK];
    }
    T[(size_t)t * 48 + mat * 16 + r] = acc;
}

// ---------------- K2/K7: bf16 GEMM, 2-phase dbuf — THE ONLY CHANGE vs round-2 ----------------
template <int OUT_BF16>
__global__ __launch_bounds__(256) void gemm_bt_kernel(const u16* __restrict__ A,
                                                      const u16* __restrict__ BT,
                                                      void* __restrict__ Cp,
                                                      int Mstore, int N, int K) {
    __shared__ __align__(16) u16 As[2][128 * 32];
    __shared__ __align__(16) u16 Bs[2][128 * 32];
    int tid = threadIdx.x;
    int m0 = blockIdx.y * 128, n0 = blockIdx.x * 128;
    int lane = tid & 63, w = tid >> 6, lr = lane & 15, lg = lane >> 4;
    int wr = w >> 1, wc = w & 1;
    int arow = tid >> 2, acol = (tid & 3) * 8;
    const u16* Ab = A + (size_t)(m0 + arow) * K + acol;
    const u16* Bb = BT + (size_t)(n0 + arow) * K + acol;
    fv4 acc[4][4] = {};
    int nt = K / 32;
#define GSTAGE(buf, kk)                                                             \
    {                                                                               \
        char* Ad = (char*)&As[buf][0] + w * 1024;                                   \
        char* Bd = (char*)&Bs[buf][0] + w * 1024;                                   \
        gload_lds16(Ab + (kk), Ad);                                                 \
        gload_lds16(Ab + (size_t)64 * K + (kk), Ad + 4096);                         \
        gload_lds16(Bb + (kk), Bd);                                                 \
        gload_lds16(Bb + (size_t)64 * K + (kk), Bd + 4096);                         \
    }
    GSTAGE(0, 0)
    __syncthreads();
    int cur = 0;
    for (int t = 0; t < nt; ++t) {
        if (t + 1 < nt) GSTAGE(cur ^ 1, (t + 1) * 32)
        bf16x8 af[4], bf[4];
#pragma unroll
        for (int i = 0; i < 4; ++i) {
            af[i] = *(const bf16x8*)&As[cur][(wr * 64 + i * 16 + lr) * 32 + lg * 8];
            bf[i] = *(const bf16x8*)&Bs[cur][(wc * 64 + i * 16 + lr) * 32 + lg * 8];
        }
#pragma unroll
        for (int mi = 0; mi < 4; ++mi)
#pragma unroll
            for (int ni = 0; ni < 4; ++ni)
                acc[mi][ni] = __builtin_amdgcn_mfma_f32_16x16x32_bf16(af[mi], bf[ni], acc[mi][ni], 0, 0, 0);
        __syncthreads();
        cur ^= 1;
    }
#undef GSTAGE
#pragma unroll
    for (int mi = 0; mi < 4; ++mi)
#pragma unroll
        for (int ni = 0; ni < 4; ++ni) {
            int col = n0 + wc * 64 + ni * 16 + lr;
#pragma unroll
            for (int r = 0; r < 4; ++r) {
                int row = m0 + wr * 64 + mi * 16 + lg * 4 + r;
                if (row < Mstore) {
                    if (OUT_BF16)
                        ((u16*)Cp)[(size_t)row * N + col] = f2b(acc[mi][ni][r]);
                    else
                        ((float*)Cp)[(size_t)row * N + col] = acc[mi][ni][r];
                }
            }
        }
}

// ---------------- K3: LoRA-B add + RoPE + scatter (round-2 exact) ----------------
__global__ __launch_bounds__(256) void lorab_rope_scatter_kernel(
    const u16* __restrict__ qkv, const float* __restrict__ T,
    const float* __restrict__ Bq, const float* __restrict__ Bk, const float* __restrict__ Bv,
    const int* __restrict__ pidx, const int* __restrict__ didx,
    const float* __restrict__ ctab, const float* __restrict__ stab,
    u16* __restrict__ qp, u16* __restrict__ kp, u16* __restrict__ vp,
    float* __restrict__ qd, float* __restrict__ kd, float* __restrict__ vd) {
    int t = blockIdx.x;
    __shared__ float Ts[48];
    if (threadIdx.x < 48) Ts[threadIdx.x] = T[(size_t)t * 48 + threadIdx.x];
    __syncthreads();
    bool pre = t < TP;
    int a = pre ? pidx[t >> 10] : didx[t - TP];
    int pos = pre ? (t & 1023) : L_CTX;
    int b = t >> 10;
    int td = t - TP;
    const u16* qrow = qkv + (size_t)t * QKV_DIM;
    for (int p = threadIdx.x; p < 3072; p += 256) {
        if (p < 2048) {  // Q
            int h = p >> 6, d = p & 63;
            int col = h * 128 + d;
            float v1 = b2f(qrow[col]), v2 = b2f(qrow[col + 64]);
            const float* B = Bq + (size_t)a * RANK * Q_DIM;
            float l1 = 0.f, l2 = 0.f;
#pragma unroll
            for (int r = 0; r < 16; ++r) {
                float tv = Ts[r];
                l1 += tv * B[(size_t)r * Q_DIM + col];
                l2 += tv * B[(size_t)r * Q_DIM + col + 64];
            }
            v1 += LORA_SCALE * l1; v2 += LORA_SCALE * l2;
            float c = ctab[pos * 64 + d], s = stab[pos * 64 + d];
            float o1 = v1 * c - v2 * s, o2 = v2 * c + v1 * s;
            if (pre) {
                size_t base = (((size_t)(b * 32 + h)) * 1024 + pos) * 128 + d;
                qp[base] = f2b(o1); qp[base + 64] = f2b(o2);
            } else {
                size_t base = ((size_t)(td * 32 + h)) * 128 + d;
                qd[base] = o1; qd[base + 64] = o2;
            }
        } else if (p < 2560) {  // K
            int pp = p - 2048;
            int h = pp >> 6, d = pp & 63;
            int jc = h * 128 + d;
            int col = Q_DIM + jc;
            float v1 = b2f(qrow[col]), v2 = b2f(qrow[col + 64]);
            const float* B = Bk + (size_t)a * RANK * KV_DIM;
            float l1 = 0.f, l2 = 0.f;
#pragma unroll
            for (int r = 0; r < 16; ++r) {
                float tv = Ts[16 + r];
                l1 += tv * B[(size_t)r * KV_DIM + jc];
                l2 += tv * B[(size_t)r * KV_DIM + jc + 64];
            }
            v1 += LORA_SCALE * l1; v2 += LORA_SCALE * l2;
            float c = ctab[pos * 64 + d], s = stab[pos * 64 + d];
            float o1 = v1 * c - v2 * s, o2 = v2 * c + v1 * s;
            if (pre) {
                size_t base = (((size_t)(b * 8 + h)) * 1024 + pos) * 128 + d;
                kp[base] = f2b(o1); kp[base + 64] = f2b(o2);
            } else {
                size_t base = ((size_t)(td * 8 + h)) * 128 + d;
                kd[base] = o1; kd[base + 64] = o2;
            }
        } else {  // V (no rope)
            int pp = p - 2560;
            int h = pp >> 6, d = pp & 63;
            int jc = h * 128 + d;
            int col = Q_DIM + KV_DIM + jc;
            float v1 = b2f(qrow[col]), v2 = b2f(qrow[col + 64]);
            const float* B = Bv + (size_t)a * RANK * KV_DIM;
            float l1 = 0.f, l2 = 0.f;
#pragma unroll
            for (int r = 0; r < 16; ++r) {
                float tv = Ts[32 + r];
                l1 += tv * B[(size_t)r * KV_DIM + jc];
                l2 += tv * B[(size_t)r * KV_DIM + jc + 64];
            }
            v1 += LORA_SCALE * l1; v2 += LORA_SCALE * l2;
            if (pre) {
                size_t base = (((size_t)(b * 8 + h)) * 1024 + pos) * 128 + d;
                vp[base] = f2b(v1); vp[base + 64] = f2b(v2);
            } else {
                size_t base = ((size_t)(td * 8 + h)) * 128 + d;
                vd[base] = v1; vd[base + 64] = v2;
            }
        }
    }
}

// ---------------- K4: prefill flash attention — round-2 EXACT version ----------------
__global__ __launch_bounds__(256) void prefill_attn_kernel(const u16* __restrict__ qp,
                                                           const u16* __restrict__ kp,
                                                           const u16* __restrict__ vp,
                                                           u16* __restrict__ attn) {
    int qblk = blockIdx.x, h = blockIdx.y, b = blockIdx.z;
    int kvh = h >> 2;
    int tid = threadIdx.x, w = tid >> 6, lane = tid & 63, lr = lane & 15, lg = lane >> 4;
    int q0 = qblk * 64 + w * 16;
    int qc = q0 + lr;
    const u16* Q = qp + ((size_t)(b * 32 + h)) * 1024 * 128;
    const u16* K = kp + ((size_t)(b * 8 + kvh)) * 1024 * 128;
    const u16* V = vp + ((size_t)(b * 8 + kvh)) * 1024 * 128;
    bf16x8 qf[4];
#pragma unroll
    for (int dc = 0; dc < 4; ++dc)
        qf[dc] = *(const bf16x8*)(Q + (size_t)qc * 128 + dc * 32 + lg * 8);
    fv4 o[8] = {};
    float m = -INFINITY, lsum = 0.f;
    int nkb = (q0 + 47) >> 5;
    for (int kb = 0; kb < nkb; ++kb) {
        int k0 = kb * 32;
        fv4 s0 = {}, s1 = {};
#pragma unroll
        for (int dc = 0; dc < 4; ++dc) {
            bf16x8 kf0 = *(const bf16x8*)(K + (size_t)(k0 + lr) * 128 + dc * 32 + lg * 8);
            bf16x8 kf1 = *(const bf16x8*)(K + (size_t)(k0 + 16 + lr) * 128 + dc * 32 + lg * 8);
            s0 = __builtin_amdgcn_mfma_f32_16x16x32_bf16(kf0, qf[dc], s0, 0, 0, 0);
            s1 = __builtin_amdgcn_mfma_f32_16x16x32_bf16(kf1, qf[dc], s1, 0, 0, 0);
        }
        float p0[4], p1[4];
        float lm = -INFINITY;
#pragma unroll
        for (int r = 0; r < 4; ++r) {
            float x = s0[r] * SCALE;
            if (k0 + lg * 4 + r > qc) x = -INFINITY;
            p0[r] = x; lm = fmaxf(lm, x);
            x = s1[r] * SCALE;
            if (k0 + 16 + lg * 4 + r > qc) x = -INFINITY;
            p1[r] = x; lm = fmaxf(lm, x);
        }
        lm = fmaxf(lm, __shfl_xor(lm, 16));
        lm = fmaxf(lm, __shfl_xor(lm, 32));
        float mn = fmaxf(m, lm);
        float sc = __expf(m - mn);
        float rs = 0.f;
#pragma unroll
        for (int r = 0; r < 4; ++r) {
            p0[r] = __expf(p0[r] - mn);
            p1[r] = __expf(p1[r] - mn);
            rs += p0[r] + p1[r];
        }
        rs += __shfl_xor(rs, 16);
        rs += __shfl_xor(rs, 32);
        lsum = lsum * sc + rs;
        m = mn;
#pragma unroll
        for (int c = 0; c < 8; ++c) o[c] *= sc;
        bf16x8 pf;
#pragma unroll
        for (int r = 0; r < 4; ++r) {
            pf[r] = (__bf16)p0[r];
            pf[4 + r] = (__bf16)p1[r];
        }
#pragma unroll
        for (int c = 0; c < 8; ++c) {
            bf16x8 vf;
#pragma unroll
            for (int i = 0; i < 4; ++i) {
                vf[i] = __builtin_bit_cast(__bf16, V[(size_t)(k0 + lg * 4 + i) * 128 + c * 16 + lr]);
                vf[4 + i] = __builtin_bit_cast(__bf16, V[(size_t)(k0 + 16 + lg * 4 + i) * 128 + c * 16 + lr]);
            }
            o[c] = __builtin_amdgcn_mfma_f32_16x16x32_bf16(vf, pf, o[c], 0, 0, 0);
        }
    }
    float inv = 1.0f / lsum;
    size_t trow = (size_t)(b * 1024 + qc) * Q_DIM;
#pragma unroll
    for (int c = 0; c < 8; ++c)
#pragma unroll
        for (int r = 0; r < 4; ++r) {
            int feat = h * 128 + c * 16 + lg * 4 + r;
            attn[trow + feat] = f2b(o[c][r] * inv);
        }
}

// ---------------- K5: decode attention ----------------
__global__ __launch_bounds__(512) void decode_attn_kernel(const float* __restrict__ kc,
                                                          const float* __restrict__ vc,
                                                          const float* __restrict__ qd,
                                                          const float* __restrict__ kd,
                                                          const float* __restrict__ vd,
                                                          const float* __restrict__ ctab,
                                                          const float* __restrict__ stab,
                                                          u16* __restrict__ attn) {
    int blk = blockIdx.x;
    int b = blk >> 3, kvh = blk & 7;
    int tid = threadIdx.x, wv = tid >> 6, lane = tid & 63;
    float q1[4], q2[4];
#pragma unroll
    for (int g = 0; g < 4; ++g) {
        size_t qb = ((size_t)(b * 32 + kvh * 4 + g)) * 128;
        q1[g] = qd[qb + lane];
        q2[g] = qd[qb + 64 + lane];
    }
    float m[4], l[4], o1[4], o2[4];
#pragma unroll
    for (int g = 0; g < 4; ++g) { m[g] = -INFINITY; l[g] = 0.f; o1[g] = 0.f; o2[g] = 0.f; }
    for (int key = wv; key <= L_CTX; key += 8) {
        float kr1, kr2, v1, v2;
        if (key < L_CTX) {
            size_t base = (((size_t)b * L_CTX + key) * 8 + kvh) * 128;
            float k1 = kc[base + lane], k2 = kc[base + 64 + lane];
            float c = ctab[key * 64 + lane], s = stab[key * 64 + lane];
            kr1 = k1 * c - k2 * s;
            kr2 = k2 * c + k1 * s;
            v1 = vc[base + lane];
            v2 = vc[base + 64 + lane];
        } else {
            size_t base = ((size_t)(b * 8 + kvh)) * 128;
            kr1 = kd[base + lane]; kr2 = kd[base + 64 + lane];
            v1 = vd[base + lane]; v2 = vd[base + 64 + lane];
        }
#pragma unroll
        for (int g = 0; g < 4; ++g) {
            float part = q1[g] * kr1 + q2[g] * kr2;
#pragma unroll
            for (int off = 32; off; off >>= 1) part += __shfl_xor(part, off);
            float sg = part * SCALE;
            float mn = fmaxf(m[g], sg);
            float sc = __expf(m[g] - mn);
            float p = __expf(sg - mn);
            l[g] = l[g] * sc + p;
            o1[g] = o1[g] * sc + p * v1;
            o2[g] = o2[g] * sc + p * v2;
            m[g] = mn;
        }
    }
    __shared__ float lm[8][4], ll[8][4];
    __shared__ float lo[8][4][128];
#pragma unroll
    for (int g = 0; g < 4; ++g) {
        lo[wv][g][lane] = o1[g];
        lo[wv][g][64 + lane] = o2[g];
    }
    if (lane == 0)
#pragma unroll
        for (int g = 0; g < 4; ++g) { lm[wv][g] = m[g]; ll[wv][g] = l[g]; }
    __syncthreads();
    int g = tid >> 7, d = tid & 127;
    float M = -INFINITY;
#pragma unroll
    for (int wvi = 0; wvi < 8; ++wvi) M = fmaxf(M, lm[wvi][g]);
    float L = 0.f, O = 0.f;
#pragma unroll
    for (int wvi = 0; wvi < 8; ++wvi) {
        float e = __expf(lm[wvi][g] - M);
        L += ll[wvi][g] * e;
        O += lo[wvi][g][d] * e;
    }
    attn[(size_t)(TP + b) * Q_DIM + (kvh * 4 + g) * 128 + d] = f2b(O / L);
}

// ---------------- K6: LoRA-A for output — round-2 scalar version ----------------
__global__ void lora_o_a_kernel(const u16* __restrict__ attn, const float* __restrict__ Ao,
                                const int* __restrict__ pidx, const int* __restrict__ didx,
                                float* __restrict__ To) {
    int gid = blockIdx.x * 256 + threadIdx.x;
    if (gid >= T_TOT * RANK) return;
    int t = gid >> 4, r = gid & 15;
    int a = (t < TP) ? pidx[t >> 10] : didx[t - TP];
    const float* A = Ao + (size_t)a * Q_DIM * RANK + r;
    const u16* xr = attn + (size_t)t * Q_DIM;
    float acc = 0.f;
    for (int j = 0; j < Q_DIM; j += 4) {
        acc += b2f(xr[j]) * A[(size_t)j * RANK];
        acc += b2f(xr[j + 1]) * A[(size_t)(j + 1) * RANK];
        acc += b2f(xr[j + 2]) * A[(size_t)(j + 2) * RANK];
        acc += b2f(xr[j + 3]) * A[(size_t)(j + 3) * RANK];
    }
    To[(size_t)t * RANK + r] = acc;
}

// ---------------- K8: final LoRA-B(O) add — round-2 version ----------------
__global__ void final_lora_add_kernel(float* __restrict__ out, const float* __restrict__ To,
                                      const float* __restrict__ Bo,
                                      const int* __restrict__ pidx, const int* __restrict__ didx) {
    int gid = blockIdx.x * 256 + threadIdx.x;
    if (gid >= T_TOT * HIDDEN) return;
    int t = gid >> 12, j = gid & 4095;
    int a = (t < TP) ? pidx[t >> 10] : didx[t - TP];
    const float* B = Bo + (size_t)a * RANK * HIDDEN;
    const float* Tr = To + (size_t)t * RANK;
    float acc = 0.f;
#pragma unroll
    for (int r = 0; r < 16; ++r) acc += Tr[r] * B[(size_t)r * HIDDEN + j];
    out[gid] += LORA_SCALE * acc;
}

// ---------------- launch (round-2 order) ----------------
extern "C" void kernel_launch(void* const* d_in, const int* in_sizes, int n_in,
                              void* d_out, int out_size, void* d_ws, size_t ws_size,
                              hipStream_t stream) {
    const float* hidden = (const float*)d_in[0];
    const float* w_qkv = (const float*)d_in[1];
    const float* w_o = (const float*)d_in[2];
    const float* k_cache = (const float*)d_in[3];
    const float* v_cache = (const float*)d_in[4];
    const float* Aq = (const float*)d_in[5];
    const float* Bq = (const float*)d_in[6];
    const float* Ak = (const float*)d_in[7];
    const float* Bk = (const float*)d_in[8];
    const float* Av = (const float*)d_in[9];
    const float* Bv = (const float*)d_in[10];
    const float* Ao = (const float*)d_in[11];
    const float* Bo = (const float*)d_in[12];
    const int* pidx = (const int*)d_in[13];
    const int* didx = (const int*)d_in[14];
    float* out = (float*)d_out;

    char* ws = (char*)d_ws;
    u16* qkv = (u16*)(ws + OFF_QKV);
    u16* attn = (u16*)(ws + OFF_ATTN);
    u16* hb = (u16*)(ws + OFF_HB);
    u16* wqT = (u16*)(ws + OFF_WQT);
    u16* woT = (u16*)(ws + OFF_WOT);
    float* T = (float*)(ws + OFF_T);
    u16* qp = (u16*)(ws + OFF_QP);
    u16* kp = (u16*)(ws + OFF_KP);
    u16* vp = (u16*)(ws + OFF_VP);
    float* qd = (float*)(ws + OFF_QD);
    float* kd = (float*)(ws + OFF_KD);
    float* vd = (float*)(ws + OFF_VD);
    float* To = (float*)(ws + OFF_TO);
    float* ctab = (float*)(ws + OFF_COS);
    float* stab = (float*)(ws + OFF_SIN);

    rope_tab_kernel<<<513, 256, 0, stream>>>(ctab, stab);
    conv_hidden_kernel<<<(M_PAD * (HIDDEN / 8) + 255) / 256, 256, 0, stream>>>(hidden, hb);
    transpose_f32_bf16_kernel<<<dim3(QKV_DIM / 64, HIDDEN / 64), 256, 0, stream>>>(w_qkv, wqT, HIDDEN, QKV_DIM);
    lora_a_kernel<<<(3 * T_TOT * RANK + 255) / 256, 256, 0, stream>>>(hidden, Aq, Ak, Av, pidx, didx, T);
    gemm_bt_kernel<1><<<dim3(QKV_DIM / 128, M_PAD / 128), 256, 0, stream>>>(hb, wqT, qkv, M_PAD, QKV_DIM, HIDDEN);
    lorab_rope_scatter_kernel<<<T_TOT, 256, 0, stream>>>(qkv, T, Bq, Bk, Bv, pidx, didx,
                                                         ctab, stab, qp, kp, vp, qd, kd, vd);
    prefill_attn_kernel<<<dim3(16, 32, 4), 256, 0, stream>>>(qp, kp, vp, attn);
    decode_attn_kernel<<<512, 512, 0, stream>>>(k_cache, v_cache, qd, kd, vd, ctab, stab, attn);
    transpose_f32_bf16_kernel<<<dim3(HIDDEN / 64, Q_DIM / 64), 256, 0, stream>>>(w_o, woT, Q_DIM, HIDDEN);
    lora_o_a_kernel<<<(T_TOT * RANK + 255) / 256, 256, 0, stream>>>(attn, Ao, pidx, didx, To);
    gemm_bt_kernel<0><<<dim3(HIDDEN / 128, M_PAD / 128), 256, 0, stream>>>(attn, woT, out, T_TOT, HIDDEN, Q_DIM);
    final_lora_add_kernel<<<(T_TOT * HIDDEN + 255) / 256, 256, 0, stream>>>(out, To, Bo, pidx, didx);
}

// Round 8
// 1663.627 us; speedup vs baseline: 1.8831x; 1.0624x over previous
//
#include <hip/hip_runtime.h>

// ---------------- constants ----------------
#define NUM_HEADS 32
#define KV_HEADS 8
#define HEAD_DIM 128
#define HIDDEN 4096
#define Q_DIM 4096
#define KV_DIM 1024
#define QKV_DIM 6144
#define GROUP 4
#define BP 4
#define S_LEN 1024
#define BD 64
#define L_CTX 2048
#define RANK 16
#define NA 8
#define TP (BP * S_LEN)      // 4096
#define T_TOT (TP + BD)      // 4160
#define M_PAD 4224           // T_TOT padded to 128 multiple
#define SCALE 0.08838834764831845f
#define LORA_SCALE 0.5f

typedef float fv4 __attribute__((ext_vector_type(4)));
typedef __bf16 bf16x8 __attribute__((ext_vector_type(8)));
typedef unsigned short usv4 __attribute__((ext_vector_type(4)));
typedef unsigned short u16;

__device__ __forceinline__ float b2f(u16 u) {
    unsigned int x = ((unsigned int)u) << 16;
    return __builtin_bit_cast(float, x);
}
__device__ __forceinline__ u16 f2b(float f) {
    unsigned int u = __builtin_bit_cast(unsigned int, f);
    unsigned int r = u + 0x7fffu + ((u >> 16) & 1u);
    return (u16)(r >> 16);
}
__device__ __forceinline__ void gload_lds16(const void* g, void* l) {
    __builtin_amdgcn_global_load_lds((const __attribute__((address_space(1))) void*)g,
                                     (__attribute__((address_space(3))) void*)l, 16, 0, 0);
}

// ---------------- workspace layout (bytes) — EXACT round-7 passing layout ----------------
#define OFF_QKV  ((size_t)0)                  // [4224][6144] bf16 ; attn alias [4224][4096] bf16
#define OFF_ATTN OFF_QKV
#define OFF_HB   ((size_t)51904512)           // hidden bf16 [4224][4096] (alias qp, then woT)
#define OFF_QP   OFF_HB
#define OFF_WOT  OFF_HB
#define OFF_WQT  ((size_t)86507520)           // wqkvT bf16 [6144][4096] (alias kp/vp/qd/kd/vd after K2)
#define OFF_KP   ((size_t)86507520)
#define OFF_VP   ((size_t)94896128)
#define OFF_QD   ((size_t)103284736)
#define OFF_KD   ((size_t)104333312)
#define OFF_VD   ((size_t)104595456)
#define OFF_T    ((size_t)136839168)          // T [4160][48] f32
#define OFF_TO   ((size_t)137637888)          // To [4160][16] f32
#define OFF_COS  ((size_t)137904128)
#define OFF_SIN  ((size_t)138428672)          // total 138,953,216 (proven bound)

// ---------------- K0: rope tables ----------------
__global__ void rope_tab_kernel(float* ctab, float* stab) {
    int idx = blockIdx.x * 256 + threadIdx.x;
    if (idx >= 2049 * 64) return;
    int pos = idx >> 6, d = idx & 63;
    float inv = 1.0f / powf(10000.0f, (float)d / 64.0f);
    float f = (float)pos * inv;
    ctab[idx] = cosf(f);
    stab[idx] = sinf(f);
}

// ---------------- Kc: hidden f32 -> bf16 (padded rows zeroed) ----------------
__global__ void conv_hidden_kernel(const float* __restrict__ x, u16* __restrict__ y) {
    int gid = blockIdx.x * 256 + threadIdx.x;
    if (gid >= M_PAD * (HIDDEN / 8)) return;
    size_t base = (size_t)gid * 8;
    int row = gid >> 9;
    usv4 lo, hi;
    if (row < T_TOT) {
        fv4 a = *(const fv4*)(x + base);
        fv4 b = *(const fv4*)(x + base + 4);
        lo[0] = f2b(a[0]); lo[1] = f2b(a[1]); lo[2] = f2b(a[2]); lo[3] = f2b(a[3]);
        hi[0] = f2b(b[0]); hi[1] = f2b(b[1]); hi[2] = f2b(b[2]); hi[3] = f2b(b[3]);
    } else {
        lo[0] = 0; lo[1] = 0; lo[2] = 0; lo[3] = 0;
        hi[0] = 0; hi[1] = 0; hi[2] = 0; hi[3] = 0;
    }
    *(usv4*)(y + base) = lo;
    *(usv4*)(y + base + 4) = hi;
}

// ---------------- Kt: transpose f32 [R][C] -> bf16 [C][R] ----------------
__global__ __launch_bounds__(256) void transpose_f32_bf16_kernel(const float* __restrict__ in,
                                                                 u16* __restrict__ out,
                                                                 int R, int C) {
    __shared__ float tile[64][65];
    int r0 = blockIdx.y * 64, c0 = blockIdx.x * 64;
    int t = threadIdx.x;
    int tr = t >> 4, tc4 = (t & 15) * 4;
#pragma unroll
    for (int it = 0; it < 4; ++it) {
        int r = tr + it * 16;
        fv4 v = *(const fv4*)(in + (size_t)(r0 + r) * C + c0 + tc4);
        tile[r][tc4 + 0] = v[0]; tile[r][tc4 + 1] = v[1];
        tile[r][tc4 + 2] = v[2]; tile[r][tc4 + 3] = v[3];
    }
    __syncthreads();
#pragma unroll
    for (int it = 0; it < 4; ++it) {
        int c = tr + it * 16;
        usv4 st;
        st[0] = f2b(tile[tc4 + 0][c]); st[1] = f2b(tile[tc4 + 1][c]);
        st[2] = f2b(tile[tc4 + 2][c]); st[3] = f2b(tile[tc4 + 3][c]);
        *(usv4*)(out + (size_t)(c0 + c) * R + r0 + tc4) = st;
    }
}

// ---------------- K1: LoRA-A ranks (q,k,v) — LDS-staged, 4 tokens/block ----------------
__global__ __launch_bounds__(256) void lora_a_kernel(const float* __restrict__ x,
                              const float* __restrict__ Aq, const float* __restrict__ Ak,
                              const float* __restrict__ Av,
                              const int* __restrict__ pidx, const int* __restrict__ didx,
                              float* __restrict__ T) {
    __shared__ float xs[4][HIDDEN];
    int t0 = blockIdx.x * 4;
    int tid = threadIdx.x;
    for (int j = tid; j < 4096; j += 256) {  // 4096 fv4 chunks (4 tokens x 1024)
        int tok = j >> 10, off = (j & 1023) * 4;
        *(fv4*)&xs[tok][off] = *(const fv4*)(x + (size_t)(t0 + tok) * HIDDEN + off);
    }
    __syncthreads();
    int w = tid >> 6, lane = tid & 63;
    if (w >= 3) return;
    const float* Ab = (w == 0) ? Aq : (w == 1 ? Ak : Av);
    float acc[4][16];
#pragma unroll
    for (int tk = 0; tk < 4; ++tk)
#pragma unroll
        for (int r = 0; r < 16; ++r) acc[tk][r] = 0.f;
#pragma unroll
    for (int tk = 0; tk < 4; ++tk) {
        int t = t0 + tk;
        int a = (t < TP) ? pidx[t >> 10] : didx[t - TP];
        const float* A = Ab + (size_t)a * HIDDEN * RANK;
        for (int i = 0; i < 64; ++i) {
            int hh = i * 64 + lane;
            float xv = xs[tk][hh];
            const float* Ar = A + (size_t)hh * RANK;
            fv4 a0 = *(const fv4*)Ar, a1 = *(const fv4*)(Ar + 4);
            fv4 a2 = *(const fv4*)(Ar + 8), a3 = *(const fv4*)(Ar + 12);
#pragma unroll
            for (int r = 0; r < 4; ++r) {
                acc[tk][r] += xv * a0[r];
                acc[tk][4 + r] += xv * a1[r];
                acc[tk][8 + r] += xv * a2[r];
                acc[tk][12 + r] += xv * a3[r];
            }
        }
    }
#pragma unroll
    for (int tk = 0; tk < 4; ++tk)
#pragma unroll
        for (int r = 0; r < 16; ++r) {
            float v = acc[tk][r];
            v += __shfl_xor(v, 1); v += __shfl_xor(v, 2); v += __shfl_xor(v, 4);
            v += __shfl_xor(v, 8); v += __shfl_xor(v, 16); v += __shfl_xor(v, 32);
            if (lane == r) T[(size_t)(t0 + tk) * 48 + w * 16 + r] = v;
        }
}

// ---------------- K2/K7: bf16 GEMM, 2-phase dbuf (round-7 proven) ----------------
template <int OUT_BF16>
__global__ __launch_bounds__(256) void gemm_bt_kernel(const u16* __restrict__ A,
                                                      const u16* __restrict__ BT,
                                                      void* __restrict__ Cp,
                                                      int Mstore, int N, int K) {
    __shared__ __align__(16) u16 As[2][128 * 32];
    __shared__ __align__(16) u16 Bs[2][128 * 32];
    int tid = threadIdx.x;
    int m0 = blockIdx.y * 128, n0 = blockIdx.x * 128;
    int lane = tid & 63, w = tid >> 6, lr = lane & 15, lg = lane >> 4;
    int wr = w >> 1, wc = w & 1;
    int arow = tid >> 2, acol = (tid & 3) * 8;
    const u16* Ab = A + (size_t)(m0 + arow) * K + acol;
    const u16* Bb = BT + (size_t)(n0 + arow) * K + acol;
    fv4 acc[4][4] = {};
    int nt = K / 32;
#define GSTAGE(buf, kk)                                                             \
    {                                                                               \
        char* Ad = (char*)&As[buf][0] + w * 1024;                                   \
        char* Bd = (char*)&Bs[buf][0] + w * 1024;                                   \
        gload_lds16(Ab + (kk), Ad);                                                 \
        gload_lds16(Ab + (size_t)64 * K + (kk), Ad + 4096);                         \
        gload_lds16(Bb + (kk), Bd);                                                 \
        gload_lds16(Bb + (size_t)64 * K + (kk), Bd + 4096);                         \
    }
    GSTAGE(0, 0)
    __syncthreads();
    int cur = 0;
    for (int t = 0; t < nt; ++t) {
        if (t + 1 < nt) GSTAGE(cur ^ 1, (t + 1) * 32)
        bf16x8 af[4], bf[4];
#pragma unroll
        for (int i = 0; i < 4; ++i) {
            af[i] = *(const bf16x8*)&As[cur][(wr * 64 + i * 16 + lr) * 32 + lg * 8];
            bf[i] = *(const bf16x8*)&Bs[cur][(wc * 64 + i * 16 + lr) * 32 + lg * 8];
        }
#pragma unroll
        for (int mi = 0; mi < 4; ++mi)
#pragma unroll
            for (int ni = 0; ni < 4; ++ni)
                acc[mi][ni] = __builtin_amdgcn_mfma_f32_16x16x32_bf16(af[mi], bf[ni], acc[mi][ni], 0, 0, 0);
        __syncthreads();
        cur ^= 1;
    }
#undef GSTAGE
#pragma unroll
    for (int mi = 0; mi < 4; ++mi)
#pragma unroll
        for (int ni = 0; ni < 4; ++ni) {
            int col = n0 + wc * 64 + ni * 16 + lr;
#pragma unroll
            for (int r = 0; r < 4; ++r) {
                int row = m0 + wr * 64 + mi * 16 + lg * 4 + r;
                if (row < Mstore) {
                    if (OUT_BF16)
                        ((u16*)Cp)[(size_t)row * N + col] = f2b(acc[mi][ni][r]);
                    else
                        ((float*)Cp)[(size_t)row * N + col] = acc[mi][ni][r];
                }
            }
        }
}

// ---------------- K3: LoRA-B add + RoPE + scatter (round-7 exact) ----------------
__global__ __launch_bounds__(256) void lorab_rope_scatter_kernel(
    const u16* __restrict__ qkv, const float* __restrict__ T,
    const float* __restrict__ Bq, const float* __restrict__ Bk, const float* __restrict__ Bv,
    const int* __restrict__ pidx, const int* __restrict__ didx,
    const float* __restrict__ ctab, const float* __restrict__ stab,
    u16* __restrict__ qp, u16* __restrict__ kp, u16* __restrict__ vp,
    float* __restrict__ qd, float* __restrict__ kd, float* __restrict__ vd) {
    int t = blockIdx.x;
    __shared__ float Ts[48];
    if (threadIdx.x < 48) Ts[threadIdx.x] = T[(size_t)t * 48 + threadIdx.x];
    __syncthreads();
    bool pre = t < TP;
    int a = pre ? pidx[t >> 10] : didx[t - TP];
    int pos = pre ? (t & 1023) : L_CTX;
    int b = t >> 10;
    int td = t - TP;
    const u16* qrow = qkv + (size_t)t * QKV_DIM;
    for (int p = threadIdx.x; p < 3072; p += 256) {
        if (p < 2048) {  // Q
            int h = p >> 6, d = p & 63;
            int col = h * 128 + d;
            float v1 = b2f(qrow[col]), v2 = b2f(qrow[col + 64]);
            const float* B = Bq + (size_t)a * RANK * Q_DIM;
            float l1 = 0.f, l2 = 0.f;
#pragma unroll
            for (int r = 0; r < 16; ++r) {
                float tv = Ts[r];
                l1 += tv * B[(size_t)r * Q_DIM + col];
                l2 += tv * B[(size_t)r * Q_DIM + col + 64];
            }
            v1 += LORA_SCALE * l1; v2 += LORA_SCALE * l2;
            float c = ctab[pos * 64 + d], s = stab[pos * 64 + d];
            float o1 = v1 * c - v2 * s, o2 = v2 * c + v1 * s;
            if (pre) {
                size_t base = (((size_t)(b * 32 + h)) * 1024 + pos) * 128 + d;
                qp[base] = f2b(o1); qp[base + 64] = f2b(o2);
            } else {
                size_t base = ((size_t)(td * 32 + h)) * 128 + d;
                qd[base] = o1; qd[base + 64] = o2;
            }
        } else if (p < 2560) {  // K
            int pp = p - 2048;
            int h = pp >> 6, d = pp & 63;
            int jc = h * 128 + d;
            int col = Q_DIM + jc;
            float v1 = b2f(qrow[col]), v2 = b2f(qrow[col + 64]);
            const float* B = Bk + (size_t)a * RANK * KV_DIM;
            float l1 = 0.f, l2 = 0.f;
#pragma unroll
            for (int r = 0; r < 16; ++r) {
                float tv = Ts[16 + r];
                l1 += tv * B[(size_t)r * KV_DIM + jc];
                l2 += tv * B[(size_t)r * KV_DIM + jc + 64];
            }
            v1 += LORA_SCALE * l1; v2 += LORA_SCALE * l2;
            float c = ctab[pos * 64 + d], s = stab[pos * 64 + d];
            float o1 = v1 * c - v2 * s, o2 = v2 * c + v1 * s;
            if (pre) {
                size_t base = (((size_t)(b * 8 + h)) * 1024 + pos) * 128 + d;
                kp[base] = f2b(o1); kp[base + 64] = f2b(o2);
            } else {
                size_t base = ((size_t)(td * 8 + h)) * 128 + d;
                kd[base] = o1; kd[base + 64] = o2;
            }
        } else {  // V (no rope)
            int pp = p - 2560;
            int h = pp >> 6, d = pp & 63;
            int jc = h * 128 + d;
            int col = Q_DIM + KV_DIM + jc;
            float v1 = b2f(qrow[col]), v2 = b2f(qrow[col + 64]);
            const float* B = Bv + (size_t)a * RANK * KV_DIM;
            float l1 = 0.f, l2 = 0.f;
#pragma unroll
            for (int r = 0; r < 16; ++r) {
                float tv = Ts[32 + r];
                l1 += tv * B[(size_t)r * KV_DIM + jc];
                l2 += tv * B[(size_t)r * KV_DIM + jc + 64];
            }
            v1 += LORA_SCALE * l1; v2 += LORA_SCALE * l2;
            if (pre) {
                size_t base = (((size_t)(b * 8 + h)) * 1024 + pos) * 128 + d;
                vp[base] = f2b(v1); vp[base + 64] = f2b(v2);
            } else {
                size_t base = ((size_t)(td * 8 + h)) * 128 + d;
                vd[base] = v1; vd[base + 64] = v2;
            }
        }
    }
}

// ---------------- K4: prefill flash attention — 32 q-rows/wave, 4 heads (one kvh) per block ----------------
// Same proven R7 access patterns (global K/V gathers, no LDS). Changes: 2 S-subtiles per
// wave (V/K frags amortized), heads of one GQA group share a block (L1/L2 K/V reuse),
// V gathers hoisted before softmax, work-balanced qt pairing.
__global__ __launch_bounds__(256) void prefill_attn_kernel(const u16* __restrict__ qp,
                                                           const u16* __restrict__ kp,
                                                           const u16* __restrict__ vp,
                                                           u16* __restrict__ attn) {
    int bx = blockIdx.x;                       // 0..31
    int qt = (bx & 1) ? (31 - (bx >> 1)) : (bx >> 1);   // pair low/high work
    int kvh = blockIdx.y, b = blockIdx.z;
    int tid = threadIdx.x, w = tid >> 6, lane = tid & 63, lr = lane & 15, lg = lane >> 4;
    int h = kvh * 4 + w;
    const u16* Q = qp + ((size_t)(b * 32 + h)) * 1024 * 128;
    const u16* K = kp + ((size_t)(b * 8 + kvh)) * 1024 * 128;
    const u16* V = vp + ((size_t)(b * 8 + kvh)) * 1024 * 128;
    int qc0 = qt * 32 + lr, qc1 = qt * 32 + 16 + lr;
    bf16x8 qf0[4], qf1[4];
#pragma unroll
    for (int dc = 0; dc < 4; ++dc) {
        qf0[dc] = *(const bf16x8*)(Q + (size_t)qc0 * 128 + dc * 32 + lg * 8);
        qf1[dc] = *(const bf16x8*)(Q + (size_t)qc1 * 128 + dc * 32 + lg * 8);
    }
    fv4 o0[8] = {}, o1[8] = {};
    float m0 = -INFINITY, l0 = 0.f;
    float m1 = -INFINITY, l1 = 0.f;
    int nkb = qt + 1;
    for (int kb = 0; kb < nkb; ++kb) {
        int k0 = kb * 32;
        fv4 s00 = {}, s10 = {}, s01 = {}, s11 = {};
#pragma unroll
        for (int dc = 0; dc < 4; ++dc) {
            bf16x8 kf0 = *(const bf16x8*)(K + (size_t)(k0 + lr) * 128 + dc * 32 + lg * 8);
            bf16x8 kf1 = *(const bf16x8*)(K + (size_t)(k0 + 16 + lr) * 128 + dc * 32 + lg * 8);
            s00 = __builtin_amdgcn_mfma_f32_16x16x32_bf16(kf0, qf0[dc], s00, 0, 0, 0);
            s10 = __builtin_amdgcn_mfma_f32_16x16x32_bf16(kf1, qf0[dc], s10, 0, 0, 0);
            s01 = __builtin_amdgcn_mfma_f32_16x16x32_bf16(kf0, qf1[dc], s01, 0, 0, 0);
            s11 = __builtin_amdgcn_mfma_f32_16x16x32_bf16(kf1, qf1[dc], s11, 0, 0, 0);
        }
        // V prefetch into registers (issue-early; hides under softmax VALU chain)
        bf16x8 vf[8];
#pragma unroll
        for (int c = 0; c < 8; ++c)
#pragma unroll
            for (int i = 0; i < 4; ++i) {
                vf[c][i] = __builtin_bit_cast(__bf16, V[(size_t)(k0 + lg * 4 + i) * 128 + c * 16 + lr]);
                vf[c][4 + i] = __builtin_bit_cast(__bf16, V[(size_t)(k0 + 16 + lg * 4 + i) * 128 + c * 16 + lr]);
            }
        // ---- softmax subtile 0 ----
        bf16x8 pf0, pf1;
        {
            float p0[4], p1[4];
            float lm = -INFINITY;
#pragma unroll
            for (int r = 0; r < 4; ++r) {
                float x = s00[r] * SCALE;
                if (k0 + lg * 4 + r > qc0) x = -INFINITY;
                p0[r] = x; lm = fmaxf(lm, x);
                x = s10[r] * SCALE;
                if (k0 + 16 + lg * 4 + r > qc0) x = -INFINITY;
                p1[r] = x; lm = fmaxf(lm, x);
            }
            lm = fmaxf(lm, __shfl_xor(lm, 16));
            lm = fmaxf(lm, __shfl_xor(lm, 32));
            float mn = fmaxf(m0, lm);
            float sc = __expf(m0 - mn);
            float rs = 0.f;
#pragma unroll
            for (int r = 0; r < 4; ++r) {
                p0[r] = __expf(p0[r] - mn);
                p1[r] = __expf(p1[r] - mn);
                rs += p0[r] + p1[r];
            }
            rs += __shfl_xor(rs, 16);
            rs += __shfl_xor(rs, 32);
            l0 = l0 * sc + rs;
            m0 = mn;
#pragma unroll
            for (int c = 0; c < 8; ++c) o0[c] *= sc;
#pragma unroll
            for (int r = 0; r < 4; ++r) {
                pf0[r] = (__bf16)p0[r];
                pf0[4 + r] = (__bf16)p1[r];
            }
        }
        // ---- softmax subtile 1 ----
        {
            float p0[4], p1[4];
            float lm = -INFINITY;
#pragma unroll
            for (int r = 0; r < 4; ++r) {
                float x = s01[r] * SCALE;
                if (k0 + lg * 4 + r > qc1) x = -INFINITY;
                p0[r] = x; lm = fmaxf(lm, x);
                x = s11[r] * SCALE;
                if (k0 + 16 + lg * 4 + r > qc1) x = -INFINITY;
                p1[r] = x; lm = fmaxf(lm, x);
            }
            lm = fmaxf(lm, __shfl_xor(lm, 16));
            lm = fmaxf(lm, __shfl_xor(lm, 32));
            float mn = fmaxf(m1, lm);
            float sc = __expf(m1 - mn);
            float rs = 0.f;
#pragma unroll
            for (int r = 0; r < 4; ++r) {
                p0[r] = __expf(p0[r] - mn);
                p1[r] = __expf(p1[r] - mn);
                rs += p0[r] + p1[r];
            }
            rs += __shfl_xor(rs, 16);
            rs += __shfl_xor(rs, 32);
            l1 = l1 * sc + rs;
            m1 = mn;
#pragma unroll
            for (int c = 0; c < 8; ++c) o1[c] *= sc;
#pragma unroll
            for (int r = 0; r < 4; ++r) {
                pf1[r] = (__bf16)p0[r];
                pf1[4 + r] = (__bf16)p1[r];
            }
        }
        // ---- PV (shared vf across both subtiles) ----
#pragma unroll
        for (int c = 0; c < 8; ++c) {
            o0[c] = __builtin_amdgcn_mfma_f32_16x16x32_bf16(vf[c], pf0, o0[c], 0, 0, 0);
            o1[c] = __builtin_amdgcn_mfma_f32_16x16x32_bf16(vf[c], pf1, o1[c], 0, 0, 0);
        }
    }
    float inv0 = 1.0f / l0, inv1 = 1.0f / l1;
    size_t trow0 = (size_t)(b * 1024 + qc0) * Q_DIM;
    size_t trow1 = (size_t)(b * 1024 + qc1) * Q_DIM;
#pragma unroll
    for (int c = 0; c < 8; ++c)
#pragma unroll
        for (int r = 0; r < 4; ++r) {
            int feat = h * 128 + c * 16 + lg * 4 + r;
            attn[trow0 + feat] = f2b(o0[c][r] * inv0);
            attn[trow1 + feat] = f2b(o1[c][r] * inv1);
        }
}

// ---------------- K5: decode attention (round-7 exact) ----------------
__global__ __launch_bounds__(512) void decode_attn_kernel(const float* __restrict__ kc,
                                                          const float* __restrict__ vc,
                                                          const float* __restrict__ qd,
                                                          const float* __restrict__ kd,
                                                          const float* __restrict__ vd,
                                                          const float* __restrict__ ctab,
                                                          const float* __restrict__ stab,
                                                          u16* __restrict__ attn) {
    int blk = blockIdx.x;
    int b = blk >> 3, kvh = blk & 7;
    int tid = threadIdx.x, wv = tid >> 6, lane = tid & 63;
    float q1[4], q2[4];
#pragma unroll
    for (int g = 0; g < 4; ++g) {
        size_t qb = ((size_t)(b * 32 + kvh * 4 + g)) * 128;
        q1[g] = qd[qb + lane];
        q2[g] = qd[qb + 64 + lane];
    }
    float m[4], l[4], o1[4], o2[4];
#pragma unroll
    for (int g = 0; g < 4; ++g) { m[g] = -INFINITY; l[g] = 0.f; o1[g] = 0.f; o2[g] = 0.f; }
    for (int key = wv; key <= L_CTX; key += 8) {
        float kr1, kr2, v1, v2;
        if (key < L_CTX) {
            size_t base = (((size_t)b * L_CTX + key) * 8 + kvh) * 128;
            float k1 = kc[base + lane], k2 = kc[base + 64 + lane];
            float c = ctab[key * 64 + lane], s = stab[key * 64 + lane];
            kr1 = k1 * c - k2 * s;
            kr2 = k2 * c + k1 * s;
            v1 = vc[base + lane];
            v2 = vc[base + 64 + lane];
        } else {
            size_t base = ((size_t)(b * 8 + kvh)) * 128;
            kr1 = kd[base + lane]; kr2 = kd[base + 64 + lane];
            v1 = vd[base + lane]; v2 = vd[base + 64 + lane];
        }
#pragma unroll
        for (int g = 0; g < 4; ++g) {
            float part = q1[g] * kr1 + q2[g] * kr2;
#pragma unroll
            for (int off = 32; off; off >>= 1) part += __shfl_xor(part, off);
            float sg = part * SCALE;
            float mn = fmaxf(m[g], sg);
            float sc = __expf(m[g] - mn);
            float p = __expf(sg - mn);
            l[g] = l[g] * sc + p;
            o1[g] = o1[g] * sc + p * v1;
            o2[g] = o2[g] * sc + p * v2;
            m[g] = mn;
        }
    }
    __shared__ float lm[8][4], ll[8][4];
    __shared__ float lo[8][4][128];
#pragma unroll
    for (int g = 0; g < 4; ++g) {
        lo[wv][g][lane] = o1[g];
        lo[wv][g][64 + lane] = o2[g];
    }
    if (lane == 0)
#pragma unroll
        for (int g = 0; g < 4; ++g) { lm[wv][g] = m[g]; ll[wv][g] = l[g]; }
    __syncthreads();
    int g = tid >> 7, d = tid & 127;
    float M = -INFINITY;
#pragma unroll
    for (int wvi = 0; wvi < 8; ++wvi) M = fmaxf(M, lm[wvi][g]);
    float L = 0.f, O = 0.f;
#pragma unroll
    for (int wvi = 0; wvi < 8; ++wvi) {
        float e = __expf(lm[wvi][g] - M);
        L += ll[wvi][g] * e;
        O += lo[wvi][g][d] * e;
    }
    attn[(size_t)(TP + b) * Q_DIM + (kvh * 4 + g) * 128 + d] = f2b(O / L);
}

// ---------------- K6: LoRA-A for output — LDS-staged, 4 tokens/block, 1 wave ----------------
__global__ __launch_bounds__(64) void lora_o_a_kernel(const u16* __restrict__ attn,
                                const float* __restrict__ Ao,
                                const int* __restrict__ pidx, const int* __restrict__ didx,
                                float* __restrict__ To) {
    __shared__ float xs[4][HIDDEN];
    int t0 = blockIdx.x * 4;
    int lane = threadIdx.x;
    for (int j = lane; j < 4096; j += 64) {  // usv4 chunks: 4 tokens x 1024
        int tok = j >> 10, off = (j & 1023) * 4;
        usv4 v = *(const usv4*)(attn + (size_t)(t0 + tok) * Q_DIM + off);
        xs[tok][off] = b2f(v[0]); xs[tok][off + 1] = b2f(v[1]);
        xs[tok][off + 2] = b2f(v[2]); xs[tok][off + 3] = b2f(v[3]);
    }
    __syncthreads();
    float acc[4][16];
#pragma unroll
    for (int tk = 0; tk < 4; ++tk)
#pragma unroll
        for (int r = 0; r < 16; ++r) acc[tk][r] = 0.f;
#pragma unroll
    for (int tk = 0; tk < 4; ++tk) {
        int t = t0 + tk;
        int a = (t < TP) ? pidx[t >> 10] : didx[t - TP];
        const float* A = Ao + (size_t)a * Q_DIM * RANK;
        for (int i = 0; i < 64; ++i) {
            int hh = i * 64 + lane;
            float xv = xs[tk][hh];
            const float* Ar = A + (size_t)hh * RANK;
            fv4 a0 = *(const fv4*)Ar, a1 = *(const fv4*)(Ar + 4);
            fv4 a2 = *(const fv4*)(Ar + 8), a3 = *(const fv4*)(Ar + 12);
#pragma unroll
            for (int r = 0; r < 4; ++r) {
                acc[tk][r] += xv * a0[r];
                acc[tk][4 + r] += xv * a1[r];
                acc[tk][8 + r] += xv * a2[r];
                acc[tk][12 + r] += xv * a3[r];
            }
        }
    }
#pragma unroll
    for (int tk = 0; tk < 4; ++tk)
#pragma unroll
        for (int r = 0; r < 16; ++r) {
            float v = acc[tk][r];
            v += __shfl_xor(v, 1); v += __shfl_xor(v, 2); v += __shfl_xor(v, 4);
            v += __shfl_xor(v, 8); v += __shfl_xor(v, 16); v += __shfl_xor(v, 32);
            if (lane == r) To[(size_t)(t0 + tk) * RANK + r] = v;
        }
}

// ---------------- K8: final LoRA-B(O) add (round-7 exact) ----------------
__global__ void final_lora_add_kernel(float* __restrict__ out, const float* __restrict__ To,
                                      const float* __restrict__ Bo,
                                      const int* __restrict__ pidx, const int* __restrict__ didx) {
    int gid = blockIdx.x * 256 + threadIdx.x;
    if (gid >= T_TOT * HIDDEN) return;
    int t = gid >> 12, j = gid & 4095;
    int a = (t < TP) ? pidx[t >> 10] : didx[t - TP];
    const float* B = Bo + (size_t)a * RANK * HIDDEN;
    const float* Tr = To + (size_t)t * RANK;
    float acc = 0.f;
#pragma unroll
    for (int r = 0; r < 16; ++r) acc += Tr[r] * B[(size_t)r * HIDDEN + j];
    out[gid] += LORA_SCALE * acc;
}

// ---------------- launch ----------------
extern "C" void kernel_launch(void* const* d_in, const int* in_sizes, int n_in,
                              void* d_out, int out_size, void* d_ws, size_t ws_size,
                              hipStream_t stream) {
    const float* hidden = (const float*)d_in[0];
    const float* w_qkv = (const float*)d_in[1];
    const float* w_o = (const float*)d_in[2];
    const float* k_cache = (const float*)d_in[3];
    const float* v_cache = (const float*)d_in[4];
    const float* Aq = (const float*)d_in[5];
    const float* Bq = (const float*)d_in[6];
    const float* Ak = (const float*)d_in[7];
    const float* Bk = (const float*)d_in[8];
    const float* Av = (const float*)d_in[9];
    const float* Bv = (const float*)d_in[10];
    const float* Ao = (const float*)d_in[11];
    const float* Bo = (const float*)d_in[12];
    const int* pidx = (const int*)d_in[13];
    const int* didx = (const int*)d_in[14];
    float* out = (float*)d_out;

    char* ws = (char*)d_ws;
    u16* qkv = (u16*)(ws + OFF_QKV);
    u16* attn = (u16*)(ws + OFF_ATTN);
    u16* hb = (u16*)(ws + OFF_HB);
    u16* wqT = (u16*)(ws + OFF_WQT);
    u16* woT = (u16*)(ws + OFF_WOT);
    float* T = (float*)(ws + OFF_T);
    u16* qp = (u16*)(ws + OFF_QP);
    u16* kp = (u16*)(ws + OFF_KP);
    u16* vp = (u16*)(ws + OFF_VP);
    float* qd = (float*)(ws + OFF_QD);
    float* kd = (float*)(ws + OFF_KD);
    float* vd = (float*)(ws + OFF_VD);
    float* To = (float*)(ws + OFF_TO);
    float* ctab = (float*)(ws + OFF_COS);
    float* stab = (float*)(ws + OFF_SIN);

    rope_tab_kernel<<<513, 256, 0, stream>>>(ctab, stab);
    conv_hidden_kernel<<<(M_PAD * (HIDDEN / 8) + 255) / 256, 256, 0, stream>>>(hidden, hb);
    transpose_f32_bf16_kernel<<<dim3(QKV_DIM / 64, HIDDEN / 64), 256, 0, stream>>>(w_qkv, wqT, HIDDEN, QKV_DIM);
    lora_a_kernel<<<T_TOT / 4, 256, 0, stream>>>(hidden, Aq, Ak, Av, pidx, didx, T);
    gemm_bt_kernel<1><<<dim3(QKV_DIM / 128, M_PAD / 128), 256, 0, stream>>>(hb, wqT, qkv, M_PAD, QKV_DIM, HIDDEN);
    lorab_rope_scatter_kernel<<<T_TOT, 256, 0, stream>>>(qkv, T, Bq, Bk, Bv, pidx, didx,
                                                         ctab, stab, qp, kp, vp, qd, kd, vd);
    prefill_attn_kernel<<<dim3(32, 8, 4), 256, 0, stream>>>(qp, kp, vp, attn);
    decode_attn_kernel<<<512, 512, 0, stream>>>(k_cache, v_cache, qd, kd, vd, ctab, stab, attn);
    transpose_f32_bf16_kernel<<<dim3(HIDDEN / 64, Q_DIM / 64), 256, 0, stream>>>(w_o, woT, Q_DIM, HIDDEN);
    lora_o_a_kernel<<<T_TOT / 4, 64, 0, stream>>>(attn, Ao, pidx, didx, To);
    gemm_bt_kernel<0><<<dim3(HIDDEN / 128, M_PAD / 128), 256, 0, stream>>>(attn, woT, out, T_TOT, HIDDEN, Q_DIM);
    final_lora_add_kernel<<<(T_TOT * HIDDEN + 255) / 256, 256, 0, stream>>>(out, To, Bo, pidx, didx);
}

// Round 9
// 1631.727 us; speedup vs baseline: 1.9199x; 1.0196x over previous
//
#include <hip/hip_runtime.h>

// ---------------- constants ----------------
#define NUM_HEADS 32
#define KV_HEADS 8
#define HEAD_DIM 128
#define HIDDEN 4096
#define Q_DIM 4096
#define KV_DIM 1024
#define QKV_DIM 6144
#define GROUP 4
#define BP 4
#define S_LEN 1024
#define BD 64
#define L_CTX 2048
#define RANK 16
#define NA 8
#define TP (BP * S_LEN)      // 4096
#define T_TOT (TP + BD)      // 4160
#define M_PAD 4224           // T_TOT padded to 128 multiple
#define SCALE 0.08838834764831845f
#define LORA_SCALE 0.5f
#define NSPLIT 4
#define SPLIT_LEN 512
// decode partial record: m[4], l[4], o[4][128] = 520 floats
#define DP_STRIDE 520

typedef float fv4 __attribute__((ext_vector_type(4)));
typedef __bf16 bf16x8 __attribute__((ext_vector_type(8)));
typedef unsigned short usv4 __attribute__((ext_vector_type(4)));
typedef unsigned short u16;

__device__ __forceinline__ float b2f(u16 u) {
    unsigned int x = ((unsigned int)u) << 16;
    return __builtin_bit_cast(float, x);
}
__device__ __forceinline__ u16 f2b(float f) {
    unsigned int u = __builtin_bit_cast(unsigned int, f);
    unsigned int r = u + 0x7fffu + ((u >> 16) & 1u);
    return (u16)(r >> 16);
}
__device__ __forceinline__ void gload_lds16(const void* g, void* l) {
    __builtin_amdgcn_global_load_lds((const __attribute__((address_space(1))) void*)g,
                                     (__attribute__((address_space(3))) void*)l, 16, 0, 0);
}

// ---------------- workspace layout (bytes) — round-7/8 proven layout + DP in dead region ----------------
#define OFF_QKV  ((size_t)0)                  // [4224][6144] bf16 ; attn alias [4224][4096] bf16
#define OFF_ATTN OFF_QKV
#define OFF_HB   ((size_t)51904512)           // hidden bf16 [4224][4096] (alias qp, then woT)
#define OFF_QP   OFF_HB
#define OFF_WOT  OFF_HB
#define OFF_WQT  ((size_t)86507520)           // wqkvT bf16 [6144][4096] (alias kp/vp/qd/kd/vd after K2)
#define OFF_KP   ((size_t)86507520)
#define OFF_VP   ((size_t)94896128)
#define OFF_QD   ((size_t)103284736)
#define OFF_KD   ((size_t)104333312)
#define OFF_VD   ((size_t)104595456)
#define OFF_DP   ((size_t)104857600)          // decode partials: 512*4*520*4 = 4,259,840 (dead wqT tail)
#define OFF_T    ((size_t)136839168)          // T [4160][48] f32
#define OFF_TO   ((size_t)137637888)          // To [4160][16] f32
#define OFF_COS  ((size_t)137904128)
#define OFF_SIN  ((size_t)138428672)          // total 138,953,216 (proven bound)

// ---------------- K0: rope tables ----------------
__global__ void rope_tab_kernel(float* ctab, float* stab) {
    int idx = blockIdx.x * 256 + threadIdx.x;
    if (idx >= 2049 * 64) return;
    int pos = idx >> 6, d = idx & 63;
    float inv = 1.0f / powf(10000.0f, (float)d / 64.0f);
    float f = (float)pos * inv;
    ctab[idx] = cosf(f);
    stab[idx] = sinf(f);
}

// ---------------- Kc: hidden f32 -> bf16 (padded rows zeroed) ----------------
__global__ void conv_hidden_kernel(const float* __restrict__ x, u16* __restrict__ y) {
    int gid = blockIdx.x * 256 + threadIdx.x;
    if (gid >= M_PAD * (HIDDEN / 8)) return;
    size_t base = (size_t)gid * 8;
    int row = gid >> 9;
    usv4 lo, hi;
    if (row < T_TOT) {
        fv4 a = *(const fv4*)(x + base);
        fv4 b = *(const fv4*)(x + base + 4);
        lo[0] = f2b(a[0]); lo[1] = f2b(a[1]); lo[2] = f2b(a[2]); lo[3] = f2b(a[3]);
        hi[0] = f2b(b[0]); hi[1] = f2b(b[1]); hi[2] = f2b(b[2]); hi[3] = f2b(b[3]);
    } else {
        lo[0] = 0; lo[1] = 0; lo[2] = 0; lo[3] = 0;
        hi[0] = 0; hi[1] = 0; hi[2] = 0; hi[3] = 0;
    }
    *(usv4*)(y + base) = lo;
    *(usv4*)(y + base + 4) = hi;
}

// ---------------- Kt: transpose f32 [R][C] -> bf16 [C][R] ----------------
__global__ __launch_bounds__(256) void transpose_f32_bf16_kernel(const float* __restrict__ in,
                                                                 u16* __restrict__ out,
                                                                 int R, int C) {
    __shared__ float tile[64][65];
    int r0 = blockIdx.y * 64, c0 = blockIdx.x * 64;
    int t = threadIdx.x;
    int tr = t >> 4, tc4 = (t & 15) * 4;
#pragma unroll
    for (int it = 0; it < 4; ++it) {
        int r = tr + it * 16;
        fv4 v = *(const fv4*)(in + (size_t)(r0 + r) * C + c0 + tc4);
        tile[r][tc4 + 0] = v[0]; tile[r][tc4 + 1] = v[1];
        tile[r][tc4 + 2] = v[2]; tile[r][tc4 + 3] = v[3];
    }
    __syncthreads();
#pragma unroll
    for (int it = 0; it < 4; ++it) {
        int c = tr + it * 16;
        usv4 st;
        st[0] = f2b(tile[tc4 + 0][c]); st[1] = f2b(tile[tc4 + 1][c]);
        st[2] = f2b(tile[tc4 + 2][c]); st[3] = f2b(tile[tc4 + 3][c]);
        *(usv4*)(out + (size_t)(c0 + c) * R + r0 + tc4) = st;
    }
}

// ---------------- K1: LoRA-A ranks (q,k,v) — LDS-staged, 4 tokens/block ----------------
__global__ __launch_bounds__(256) void lora_a_kernel(const float* __restrict__ x,
                              const float* __restrict__ Aq, const float* __restrict__ Ak,
                              const float* __restrict__ Av,
                              const int* __restrict__ pidx, const int* __restrict__ didx,
                              float* __restrict__ T) {
    __shared__ float xs[4][HIDDEN];
    int t0 = blockIdx.x * 4;
    int tid = threadIdx.x;
    for (int j = tid; j < 4096; j += 256) {
        int tok = j >> 10, off = (j & 1023) * 4;
        *(fv4*)&xs[tok][off] = *(const fv4*)(x + (size_t)(t0 + tok) * HIDDEN + off);
    }
    __syncthreads();
    int w = tid >> 6, lane = tid & 63;
    if (w >= 3) return;
    const float* Ab = (w == 0) ? Aq : (w == 1 ? Ak : Av);
    float acc[4][16];
#pragma unroll
    for (int tk = 0; tk < 4; ++tk)
#pragma unroll
        for (int r = 0; r < 16; ++r) acc[tk][r] = 0.f;
#pragma unroll
    for (int tk = 0; tk < 4; ++tk) {
        int t = t0 + tk;
        int a = (t < TP) ? pidx[t >> 10] : didx[t - TP];
        const float* A = Ab + (size_t)a * HIDDEN * RANK;
        for (int i = 0; i < 64; ++i) {
            int hh = i * 64 + lane;
            float xv = xs[tk][hh];
            const float* Ar = A + (size_t)hh * RANK;
            fv4 a0 = *(const fv4*)Ar, a1 = *(const fv4*)(Ar + 4);
            fv4 a2 = *(const fv4*)(Ar + 8), a3 = *(const fv4*)(Ar + 12);
#pragma unroll
            for (int r = 0; r < 4; ++r) {
                acc[tk][r] += xv * a0[r];
                acc[tk][4 + r] += xv * a1[r];
                acc[tk][8 + r] += xv * a2[r];
                acc[tk][12 + r] += xv * a3[r];
            }
        }
    }
#pragma unroll
    for (int tk = 0; tk < 4; ++tk)
#pragma unroll
        for (int r = 0; r < 16; ++r) {
            float v = acc[tk][r];
            v += __shfl_xor(v, 1); v += __shfl_xor(v, 2); v += __shfl_xor(v, 4);
            v += __shfl_xor(v, 8); v += __shfl_xor(v, 16); v += __shfl_xor(v, 32);
            if (lane == r) T[(size_t)(t0 + tk) * 48 + w * 16 + r] = v;
        }
}

// ---------------- K2/K7: bf16 GEMM, 2-phase dbuf (proven) ----------------
template <int OUT_BF16>
__global__ __launch_bounds__(256) void gemm_bt_kernel(const u16* __restrict__ A,
                                                      const u16* __restrict__ BT,
                                                      void* __restrict__ Cp,
                                                      int Mstore, int N, int K) {
    __shared__ __align__(16) u16 As[2][128 * 32];
    __shared__ __align__(16) u16 Bs[2][128 * 32];
    int tid = threadIdx.x;
    int m0 = blockIdx.y * 128, n0 = blockIdx.x * 128;
    int lane = tid & 63, w = tid >> 6, lr = lane & 15, lg = lane >> 4;
    int wr = w >> 1, wc = w & 1;
    int arow = tid >> 2, acol = (tid & 3) * 8;
    const u16* Ab = A + (size_t)(m0 + arow) * K + acol;
    const u16* Bb = BT + (size_t)(n0 + arow) * K + acol;
    fv4 acc[4][4] = {};
    int nt = K / 32;
#define GSTAGE(buf, kk)                                                             \
    {                                                                               \
        char* Ad = (char*)&As[buf][0] + w * 1024;                                   \
        char* Bd = (char*)&Bs[buf][0] + w * 1024;                                   \
        gload_lds16(Ab + (kk), Ad);                                                 \
        gload_lds16(Ab + (size_t)64 * K + (kk), Ad + 4096);                         \
        gload_lds16(Bb + (kk), Bd);                                                 \
        gload_lds16(Bb + (size_t)64 * K + (kk), Bd + 4096);                         \
    }
    GSTAGE(0, 0)
    __syncthreads();
    int cur = 0;
    for (int t = 0; t < nt; ++t) {
        if (t + 1 < nt) GSTAGE(cur ^ 1, (t + 1) * 32)
        bf16x8 af[4], bf[4];
#pragma unroll
        for (int i = 0; i < 4; ++i) {
            af[i] = *(const bf16x8*)&As[cur][(wr * 64 + i * 16 + lr) * 32 + lg * 8];
            bf[i] = *(const bf16x8*)&Bs[cur][(wc * 64 + i * 16 + lr) * 32 + lg * 8];
        }
#pragma unroll
        for (int mi = 0; mi < 4; ++mi)
#pragma unroll
            for (int ni = 0; ni < 4; ++ni)
                acc[mi][ni] = __builtin_amdgcn_mfma_f32_16x16x32_bf16(af[mi], bf[ni], acc[mi][ni], 0, 0, 0);
        __syncthreads();
        cur ^= 1;
    }
#undef GSTAGE
#pragma unroll
    for (int mi = 0; mi < 4; ++mi)
#pragma unroll
        for (int ni = 0; ni < 4; ++ni) {
            int col = n0 + wc * 64 + ni * 16 + lr;
#pragma unroll
            for (int r = 0; r < 4; ++r) {
                int row = m0 + wr * 64 + mi * 16 + lg * 4 + r;
                if (row < Mstore) {
                    if (OUT_BF16)
                        ((u16*)Cp)[(size_t)row * N + col] = f2b(acc[mi][ni][r]);
                    else
                        ((float*)Cp)[(size_t)row * N + col] = acc[mi][ni][r];
                }
            }
        }
}

// ---------------- K3: LoRA-B add + RoPE + scatter (proven) ----------------
__global__ __launch_bounds__(256) void lorab_rope_scatter_kernel(
    const u16* __restrict__ qkv, const float* __restrict__ T,
    const float* __restrict__ Bq, const float* __restrict__ Bk, const float* __restrict__ Bv,
    const int* __restrict__ pidx, const int* __restrict__ didx,
    const float* __restrict__ ctab, const float* __restrict__ stab,
    u16* __restrict__ qp, u16* __restrict__ kp, u16* __restrict__ vp,
    float* __restrict__ qd, float* __restrict__ kd, float* __restrict__ vd) {
    int t = blockIdx.x;
    __shared__ float Ts[48];
    if (threadIdx.x < 48) Ts[threadIdx.x] = T[(size_t)t * 48 + threadIdx.x];
    __syncthreads();
    bool pre = t < TP;
    int a = pre ? pidx[t >> 10] : didx[t - TP];
    int pos = pre ? (t & 1023) : L_CTX;
    int b = t >> 10;
    int td = t - TP;
    const u16* qrow = qkv + (size_t)t * QKV_DIM;
    for (int p = threadIdx.x; p < 3072; p += 256) {
        if (p < 2048) {  // Q
            int h = p >> 6, d = p & 63;
            int col = h * 128 + d;
            float v1 = b2f(qrow[col]), v2 = b2f(qrow[col + 64]);
            const float* B = Bq + (size_t)a * RANK * Q_DIM;
            float l1 = 0.f, l2 = 0.f;
#pragma unroll
            for (int r = 0; r < 16; ++r) {
                float tv = Ts[r];
                l1 += tv * B[(size_t)r * Q_DIM + col];
                l2 += tv * B[(size_t)r * Q_DIM + col + 64];
            }
            v1 += LORA_SCALE * l1; v2 += LORA_SCALE * l2;
            float c = ctab[pos * 64 + d], s = stab[pos * 64 + d];
            float o1 = v1 * c - v2 * s, o2 = v2 * c + v1 * s;
            if (pre) {
                size_t base = (((size_t)(b * 32 + h)) * 1024 + pos) * 128 + d;
                qp[base] = f2b(o1); qp[base + 64] = f2b(o2);
            } else {
                size_t base = ((size_t)(td * 32 + h)) * 128 + d;
                qd[base] = o1; qd[base + 64] = o2;
            }
        } else if (p < 2560) {  // K
            int pp = p - 2048;
            int h = pp >> 6, d = pp & 63;
            int jc = h * 128 + d;
            int col = Q_DIM + jc;
            float v1 = b2f(qrow[col]), v2 = b2f(qrow[col + 64]);
            const float* B = Bk + (size_t)a * RANK * KV_DIM;
            float l1 = 0.f, l2 = 0.f;
#pragma unroll
            for (int r = 0; r < 16; ++r) {
                float tv = Ts[16 + r];
                l1 += tv * B[(size_t)r * KV_DIM + jc];
                l2 += tv * B[(size_t)r * KV_DIM + jc + 64];
            }
            v1 += LORA_SCALE * l1; v2 += LORA_SCALE * l2;
            float c = ctab[pos * 64 + d], s = stab[pos * 64 + d];
            float o1 = v1 * c - v2 * s, o2 = v2 * c + v1 * s;
            if (pre) {
                size_t base = (((size_t)(b * 8 + h)) * 1024 + pos) * 128 + d;
                kp[base] = f2b(o1); kp[base + 64] = f2b(o2);
            } else {
                size_t base = ((size_t)(td * 8 + h)) * 128 + d;
                kd[base] = o1; kd[base + 64] = o2;
            }
        } else {  // V (no rope)
            int pp = p - 2560;
            int h = pp >> 6, d = pp & 63;
            int jc = h * 128 + d;
            int col = Q_DIM + KV_DIM + jc;
            float v1 = b2f(qrow[col]), v2 = b2f(qrow[col + 64]);
            const float* B = Bv + (size_t)a * RANK * KV_DIM;
            float l1 = 0.f, l2 = 0.f;
#pragma unroll
            for (int r = 0; r < 16; ++r) {
                float tv = Ts[32 + r];
                l1 += tv * B[(size_t)r * KV_DIM + jc];
                l2 += tv * B[(size_t)r * KV_DIM + jc + 64];
            }
            v1 += LORA_SCALE * l1; v2 += LORA_SCALE * l2;
            if (pre) {
                size_t base = (((size_t)(b * 8 + h)) * 1024 + pos) * 128 + d;
                vp[base] = f2b(v1); vp[base + 64] = f2b(v2);
            } else {
                size_t base = ((size_t)(td * 8 + h)) * 128 + d;
                vd[base] = v1; vd[base + 64] = v2;
            }
        }
    }
}

// ---------------- K4: prefill flash attention (round-8 proven) ----------------
__global__ __launch_bounds__(256) void prefill_attn_kernel(const u16* __restrict__ qp,
                                                           const u16* __restrict__ kp,
                                                           const u16* __restrict__ vp,
                                                           u16* __restrict__ attn) {
    int bx = blockIdx.x;
    int qt = (bx & 1) ? (31 - (bx >> 1)) : (bx >> 1);
    int kvh = blockIdx.y, b = blockIdx.z;
    int tid = threadIdx.x, w = tid >> 6, lane = tid & 63, lr = lane & 15, lg = lane >> 4;
    int h = kvh * 4 + w;
    const u16* Q = qp + ((size_t)(b * 32 + h)) * 1024 * 128;
    const u16* K = kp + ((size_t)(b * 8 + kvh)) * 1024 * 128;
    const u16* V = vp + ((size_t)(b * 8 + kvh)) * 1024 * 128;
    int qc0 = qt * 32 + lr, qc1 = qt * 32 + 16 + lr;
    bf16x8 qf0[4], qf1[4];
#pragma unroll
    for (int dc = 0; dc < 4; ++dc) {
        qf0[dc] = *(const bf16x8*)(Q + (size_t)qc0 * 128 + dc * 32 + lg * 8);
        qf1[dc] = *(const bf16x8*)(Q + (size_t)qc1 * 128 + dc * 32 + lg * 8);
    }
    fv4 o0[8] = {}, o1[8] = {};
    float m0 = -INFINITY, l0 = 0.f;
    float m1 = -INFINITY, l1 = 0.f;
    int nkb = qt + 1;
    for (int kb = 0; kb < nkb; ++kb) {
        int k0 = kb * 32;
        fv4 s00 = {}, s10 = {}, s01 = {}, s11 = {};
#pragma unroll
        for (int dc = 0; dc < 4; ++dc) {
            bf16x8 kf0 = *(const bf16x8*)(K + (size_t)(k0 + lr) * 128 + dc * 32 + lg * 8);
            bf16x8 kf1 = *(const bf16x8*)(K + (size_t)(k0 + 16 + lr) * 128 + dc * 32 + lg * 8);
            s00 = __builtin_amdgcn_mfma_f32_16x16x32_bf16(kf0, qf0[dc], s00, 0, 0, 0);
            s10 = __builtin_amdgcn_mfma_f32_16x16x32_bf16(kf1, qf0[dc], s10, 0, 0, 0);
            s01 = __builtin_amdgcn_mfma_f32_16x16x32_bf16(kf0, qf1[dc], s01, 0, 0, 0);
            s11 = __builtin_amdgcn_mfma_f32_16x16x32_bf16(kf1, qf1[dc], s11, 0, 0, 0);
        }
        bf16x8 vf[8];
#pragma unroll
        for (int c = 0; c < 8; ++c)
#pragma unroll
            for (int i = 0; i < 4; ++i) {
                vf[c][i] = __builtin_bit_cast(__bf16, V[(size_t)(k0 + lg * 4 + i) * 128 + c * 16 + lr]);
                vf[c][4 + i] = __builtin_bit_cast(__bf16, V[(size_t)(k0 + 16 + lg * 4 + i) * 128 + c * 16 + lr]);
            }
        bf16x8 pf0, pf1;
        {
            float p0[4], p1[4];
            float lm = -INFINITY;
#pragma unroll
            for (int r = 0; r < 4; ++r) {
                float x = s00[r] * SCALE;
                if (k0 + lg * 4 + r > qc0) x = -INFINITY;
                p0[r] = x; lm = fmaxf(lm, x);
                x = s10[r] * SCALE;
                if (k0 + 16 + lg * 4 + r > qc0) x = -INFINITY;
                p1[r] = x; lm = fmaxf(lm, x);
            }
            lm = fmaxf(lm, __shfl_xor(lm, 16));
            lm = fmaxf(lm, __shfl_xor(lm, 32));
            float mn = fmaxf(m0, lm);
            float sc = __expf(m0 - mn);
            float rs = 0.f;
#pragma unroll
            for (int r = 0; r < 4; ++r) {
                p0[r] = __expf(p0[r] - mn);
                p1[r] = __expf(p1[r] - mn);
                rs += p0[r] + p1[r];
            }
            rs += __shfl_xor(rs, 16);
            rs += __shfl_xor(rs, 32);
            l0 = l0 * sc + rs;
            m0 = mn;
#pragma unroll
            for (int c = 0; c < 8; ++c) o0[c] *= sc;
#pragma unroll
            for (int r = 0; r < 4; ++r) {
                pf0[r] = (__bf16)p0[r];
                pf0[4 + r] = (__bf16)p1[r];
            }
        }
        {
            float p0[4], p1[4];
            float lm = -INFINITY;
#pragma unroll
            for (int r = 0; r < 4; ++r) {
                float x = s01[r] * SCALE;
                if (k0 + lg * 4 + r > qc1) x = -INFINITY;
                p0[r] = x; lm = fmaxf(lm, x);
                x = s11[r] * SCALE;
                if (k0 + 16 + lg * 4 + r > qc1) x = -INFINITY;
                p1[r] = x; lm = fmaxf(lm, x);
            }
            lm = fmaxf(lm, __shfl_xor(lm, 16));
            lm = fmaxf(lm, __shfl_xor(lm, 32));
            float mn = fmaxf(m1, lm);
            float sc = __expf(m1 - mn);
            float rs = 0.f;
#pragma unroll
            for (int r = 0; r < 4; ++r) {
                p0[r] = __expf(p0[r] - mn);
                p1[r] = __expf(p1[r] - mn);
                rs += p0[r] + p1[r];
            }
            rs += __shfl_xor(rs, 16);
            rs += __shfl_xor(rs, 32);
            l1 = l1 * sc + rs;
            m1 = mn;
#pragma unroll
            for (int c = 0; c < 8; ++c) o1[c] *= sc;
#pragma unroll
            for (int r = 0; r < 4; ++r) {
                pf1[r] = (__bf16)p0[r];
                pf1[4 + r] = (__bf16)p1[r];
            }
        }
#pragma unroll
        for (int c = 0; c < 8; ++c) {
            o0[c] = __builtin_amdgcn_mfma_f32_16x16x32_bf16(vf[c], pf0, o0[c], 0, 0, 0);
            o1[c] = __builtin_amdgcn_mfma_f32_16x16x32_bf16(vf[c], pf1, o1[c], 0, 0, 0);
        }
    }
    float inv0 = 1.0f / l0, inv1 = 1.0f / l1;
    size_t trow0 = (size_t)(b * 1024 + qc0) * Q_DIM;
    size_t trow1 = (size_t)(b * 1024 + qc1) * Q_DIM;
#pragma unroll
    for (int c = 0; c < 8; ++c)
#pragma unroll
        for (int r = 0; r < 4; ++r) {
            int feat = h * 128 + c * 16 + lg * 4 + r;
            attn[trow0 + feat] = f2b(o0[c][r] * inv0);
            attn[trow1 + feat] = f2b(o1[c][r] * inv1);
        }
}

// ---------------- K5: decode attention — split-K (4 splits of 512 keys), writes partials ----------------
__global__ __launch_bounds__(512) void decode_attn_kernel(const float* __restrict__ kc,
                                                          const float* __restrict__ vc,
                                                          const float* __restrict__ qd,
                                                          const float* __restrict__ kd,
                                                          const float* __restrict__ vd,
                                                          const float* __restrict__ ctab,
                                                          const float* __restrict__ stab,
                                                          float* __restrict__ dp) {
    int blk = blockIdx.x;               // 0..2047
    int s = blk & 3;                    // key split
    int bk = blk >> 2;                  // (b*8+kvh)
    int b = bk >> 3, kvh = bk & 7;
    int tid = threadIdx.x, wv = tid >> 6, lane = tid & 63;
    float q1[4], q2[4];
#pragma unroll
    for (int g = 0; g < 4; ++g) {
        size_t qb = ((size_t)(b * 32 + kvh * 4 + g)) * 128;
        q1[g] = qd[qb + lane];
        q2[g] = qd[qb + 64 + lane];
    }
    float m[4], l[4], o1[4], o2[4];
#pragma unroll
    for (int g = 0; g < 4; ++g) { m[g] = -INFINITY; l[g] = 0.f; o1[g] = 0.f; o2[g] = 0.f; }
    int kbeg = s * SPLIT_LEN, kend = kbeg + SPLIT_LEN;
    // last split additionally handles the new-token key (L_CTX), on wave 0
    int klast = (s == NSPLIT - 1 && wv == 0) ? (L_CTX + 8) : kend;   // sentinel: key==L_CTX hits once
    for (int key = kbeg + wv; key < klast; key += 8) {
        if (key > L_CTX) break;
        float kr1, kr2, v1, v2;
        if (key < L_CTX) {
            size_t base = (((size_t)b * L_CTX + key) * 8 + kvh) * 128;
            float k1 = kc[base + lane], k2 = kc[base + 64 + lane];
            float c = ctab[key * 64 + lane], ssn = stab[key * 64 + lane];
            kr1 = k1 * c - k2 * ssn;
            kr2 = k2 * c + k1 * ssn;
            v1 = vc[base + lane];
            v2 = vc[base + 64 + lane];
        } else {
            size_t base = ((size_t)(b * 8 + kvh)) * 128;
            kr1 = kd[base + lane]; kr2 = kd[base + 64 + lane];
            v1 = vd[base + lane]; v2 = vd[base + 64 + lane];
        }
#pragma unroll
        for (int g = 0; g < 4; ++g) {
            float part = q1[g] * kr1 + q2[g] * kr2;
#pragma unroll
            for (int off = 32; off; off >>= 1) part += __shfl_xor(part, off);
            float sg = part * SCALE;
            float mn = fmaxf(m[g], sg);
            float sc = __expf(m[g] - mn);
            float p = __expf(sg - mn);
            l[g] = l[g] * sc + p;
            o1[g] = o1[g] * sc + p * v1;
            o2[g] = o2[g] * sc + p * v2;
            m[g] = mn;
        }
    }
    __shared__ float lm[8][4], ll[8][4];
    __shared__ float lo[8][4][128];
#pragma unroll
    for (int g = 0; g < 4; ++g) {
        lo[wv][g][lane] = o1[g];
        lo[wv][g][64 + lane] = o2[g];
    }
    if (lane == 0)
#pragma unroll
        for (int g = 0; g < 4; ++g) { lm[wv][g] = m[g]; ll[wv][g] = l[g]; }
    __syncthreads();
    int g = tid >> 7, d = tid & 127;
    float M = -INFINITY;
#pragma unroll
    for (int wvi = 0; wvi < 8; ++wvi) M = fmaxf(M, lm[wvi][g]);
    float L = 0.f, O = 0.f;
#pragma unroll
    for (int wvi = 0; wvi < 8; ++wvi) {
        float e = __expf(lm[wvi][g] - M);
        L += ll[wvi][g] * e;
        O += lo[wvi][g][d] * e;
    }
    // write partial record
    size_t base = ((size_t)(bk * NSPLIT + s)) * DP_STRIDE;
    dp[base + 8 + g * 128 + d] = O;
    if (d == 0) { dp[base + g] = M; dp[base + 4 + g] = L; }
}

// ---------------- K5b: decode split merge ----------------
__global__ void decode_merge_kernel(const float* __restrict__ dp, u16* __restrict__ attn) {
    int gid = blockIdx.x * 256 + threadIdx.x;   // 64*8*4*128 = 262144
    if (gid >= BD * KV_HEADS * 4 * 128) return;
    int d = gid & 127, g = (gid >> 7) & 3;
    int kvh = (gid >> 9) & 7, b = gid >> 12;
    int bk = b * 8 + kvh;
    float M = -INFINITY;
#pragma unroll
    for (int s = 0; s < NSPLIT; ++s)
        M = fmaxf(M, dp[((size_t)(bk * NSPLIT + s)) * DP_STRIDE + g]);
    float L = 0.f, O = 0.f;
#pragma unroll
    for (int s = 0; s < NSPLIT; ++s) {
        size_t base = ((size_t)(bk * NSPLIT + s)) * DP_STRIDE;
        float e = __expf(dp[base + g] - M);
        L += dp[base + 4 + g] * e;
        O += dp[base + 8 + g * 128 + d] * e;
    }
    attn[(size_t)(TP + b) * Q_DIM + (kvh * 4 + g) * 128 + d] = f2b(O / L);
}

// ---------------- K6: LoRA-A for output — LDS-staged, 4 tokens/block, 1 wave ----------------
__global__ __launch_bounds__(64) void lora_o_a_kernel(const u16* __restrict__ attn,
                                const float* __restrict__ Ao,
                                const int* __restrict__ pidx, const int* __restrict__ didx,
                                float* __restrict__ To) {
    __shared__ float xs[4][HIDDEN];
    int t0 = blockIdx.x * 4;
    int lane = threadIdx.x;
    for (int j = lane; j < 4096; j += 64) {
        int tok = j >> 10, off = (j & 1023) * 4;
        usv4 v = *(const usv4*)(attn + (size_t)(t0 + tok) * Q_DIM + off);
        xs[tok][off] = b2f(v[0]); xs[tok][off + 1] = b2f(v[1]);
        xs[tok][off + 2] = b2f(v[2]); xs[tok][off + 3] = b2f(v[3]);
    }
    __syncthreads();
    float acc[4][16];
#pragma unroll
    for (int tk = 0; tk < 4; ++tk)
#pragma unroll
        for (int r = 0; r < 16; ++r) acc[tk][r] = 0.f;
#pragma unroll
    for (int tk = 0; tk < 4; ++tk) {
        int t = t0 + tk;
        int a = (t < TP) ? pidx[t >> 10] : didx[t - TP];
        const float* A = Ao + (size_t)a * Q_DIM * RANK;
        for (int i = 0; i < 64; ++i) {
            int hh = i * 64 + lane;
            float xv = xs[tk][hh];
            const float* Ar = A + (size_t)hh * RANK;
            fv4 a0 = *(const fv4*)Ar, a1 = *(const fv4*)(Ar + 4);
            fv4 a2 = *(const fv4*)(Ar + 8), a3 = *(const fv4*)(Ar + 12);
#pragma unroll
            for (int r = 0; r < 4; ++r) {
                acc[tk][r] += xv * a0[r];
                acc[tk][4 + r] += xv * a1[r];
                acc[tk][8 + r] += xv * a2[r];
                acc[tk][12 + r] += xv * a3[r];
            }
        }
    }
#pragma unroll
    for (int tk = 0; tk < 4; ++tk)
#pragma unroll
        for (int r = 0; r < 16; ++r) {
            float v = acc[tk][r];
            v += __shfl_xor(v, 1); v += __shfl_xor(v, 2); v += __shfl_xor(v, 4);
            v += __shfl_xor(v, 8); v += __shfl_xor(v, 16); v += __shfl_xor(v, 32);
            if (lane == r) To[(size_t)(t0 + tk) * RANK + r] = v;
        }
}

// ---------------- K8: final LoRA-B(O) add (proven) ----------------
__global__ void final_lora_add_kernel(float* __restrict__ out, const float* __restrict__ To,
                                      const float* __restrict__ Bo,
                                      const int* __restrict__ pidx, const int* __restrict__ didx) {
    int gid = blockIdx.x * 256 + threadIdx.x;
    if (gid >= T_TOT * HIDDEN) return;
    int t = gid >> 12, j = gid & 4095;
    int a = (t < TP) ? pidx[t >> 10] : didx[t - TP];
    const float* B = Bo + (size_t)a * RANK * HIDDEN;
    const float* Tr = To + (size_t)t * RANK;
    float acc = 0.f;
#pragma unroll
    for (int r = 0; r < 16; ++r) acc += Tr[r] * B[(size_t)r * HIDDEN + j];
    out[gid] += LORA_SCALE * acc;
}

// ---------------- launch ----------------
extern "C" void kernel_launch(void* const* d_in, const int* in_sizes, int n_in,
                              void* d_out, int out_size, void* d_ws, size_t ws_size,
                              hipStream_t stream) {
    const float* hidden = (const float*)d_in[0];
    const float* w_qkv = (const float*)d_in[1];
    const float* w_o = (const float*)d_in[2];
    const float* k_cache = (const float*)d_in[3];
    const float* v_cache = (const float*)d_in[4];
    const float* Aq = (const float*)d_in[5];
    const float* Bq = (const float*)d_in[6];
    const float* Ak = (const float*)d_in[7];
    const float* Bk = (const float*)d_in[8];
    const float* Av = (const float*)d_in[9];
    const float* Bv = (const float*)d_in[10];
    const float* Ao = (const float*)d_in[11];
    const float* Bo = (const float*)d_in[12];
    const int* pidx = (const int*)d_in[13];
    const int* didx = (const int*)d_in[14];
    float* out = (float*)d_out;

    char* ws = (char*)d_ws;
    u16* qkv = (u16*)(ws + OFF_QKV);
    u16* attn = (u16*)(ws + OFF_ATTN);
    u16* hb = (u16*)(ws + OFF_HB);
    u16* wqT = (u16*)(ws + OFF_WQT);
    u16* woT = (u16*)(ws + OFF_WOT);
    float* T = (float*)(ws + OFF_T);
    u16* qp = (u16*)(ws + OFF_QP);
    u16* kp = (u16*)(ws + OFF_KP);
    u16* vp = (u16*)(ws + OFF_VP);
    float* qd = (float*)(ws + OFF_QD);
    float* kd = (float*)(ws + OFF_KD);
    float* vd = (float*)(ws + OFF_VD);
    float* dp = (float*)(ws + OFF_DP);
    float* To = (float*)(ws + OFF_TO);
    float* ctab = (float*)(ws + OFF_COS);
    float* stab = (float*)(ws + OFF_SIN);

    rope_tab_kernel<<<513, 256, 0, stream>>>(ctab, stab);
    conv_hidden_kernel<<<(M_PAD * (HIDDEN / 8) + 255) / 256, 256, 0, stream>>>(hidden, hb);
    transpose_f32_bf16_kernel<<<dim3(QKV_DIM / 64, HIDDEN / 64), 256, 0, stream>>>(w_qkv, wqT, HIDDEN, QKV_DIM);
    lora_a_kernel<<<T_TOT / 4, 256, 0, stream>>>(hidden, Aq, Ak, Av, pidx, didx, T);
    gemm_bt_kernel<1><<<dim3(QKV_DIM / 128, M_PAD / 128), 256, 0, stream>>>(hb, wqT, qkv, M_PAD, QKV_DIM, HIDDEN);
    lorab_rope_scatter_kernel<<<T_TOT, 256, 0, stream>>>(qkv, T, Bq, Bk, Bv, pidx, didx,
                                                         ctab, stab, qp, kp, vp, qd, kd, vd);
    prefill_attn_kernel<<<dim3(32, 8, 4), 256, 0, stream>>>(qp, kp, vp, attn);
    decode_attn_kernel<<<512 * NSPLIT, 512, 0, stream>>>(k_cache, v_cache, qd, kd, vd, ctab, stab, dp);
    decode_merge_kernel<<<(BD * KV_HEADS * 4 * 128 + 255) / 256, 256, 0, stream>>>(dp, attn);
    transpose_f32_bf16_kernel<<<dim3(HIDDEN / 64, Q_DIM / 64), 256, 0, stream>>>(w_o, woT, Q_DIM, HIDDEN);
    lora_o_a_kernel<<<T_TOT / 4, 64, 0, stream>>>(attn, Ao, pidx, didx, To);
    gemm_bt_kernel<0><<<dim3(HIDDEN / 128, M_PAD / 128), 256, 0, stream>>>(attn, woT, out, T_TOT, HIDDEN, Q_DIM);
    final_lora_add_kernel<<<(T_TOT * HIDDEN + 255) / 256, 256, 0, stream>>>(out, To, Bo, pidx, didx);
}

// Round 10
// 1588.473 us; speedup vs baseline: 1.9722x; 1.0272x over previous
//
#include <hip/hip_runtime.h>

// ---------------- constants ----------------
#define NUM_HEADS 32
#define KV_HEADS 8
#define HEAD_DIM 128
#define HIDDEN 4096
#define Q_DIM 4096
#define KV_DIM 1024
#define QKV_DIM 6144
#define GROUP 4
#define BP 4
#define S_LEN 1024
#define BD 64
#define L_CTX 2048
#define RANK 16
#define NA 8
#define TP (BP * S_LEN)      // 4096
#define T_TOT (TP + BD)      // 4160
#define M_PAD 4224           // T_TOT padded to 128 multiple
#define SCALE 0.08838834764831845f
#define LORA_SCALE 0.5f
#define DNSPLIT 16           // decode: 16 splits x 128 keys = 2048
#define DSPLIT_LEN 128
// decode partial record: m[4], l[4], o[4][128] = 520 floats
#define DP_STRIDE 520

typedef float fv4 __attribute__((ext_vector_type(4)));
typedef __bf16 bf16x8 __attribute__((ext_vector_type(8)));
typedef unsigned short usv4 __attribute__((ext_vector_type(4)));
typedef unsigned short u16;

__device__ __forceinline__ float b2f(u16 u) {
    unsigned int x = ((unsigned int)u) << 16;
    return __builtin_bit_cast(float, x);
}
__device__ __forceinline__ u16 f2b(float f) {
    unsigned int u = __builtin_bit_cast(unsigned int, f);
    unsigned int r = u + 0x7fffu + ((u >> 16) & 1u);
    return (u16)(r >> 16);
}
__device__ __forceinline__ void gload_lds16(const void* g, void* l) {
    __builtin_amdgcn_global_load_lds((const __attribute__((address_space(1))) void*)g,
                                     (__attribute__((address_space(3))) void*)l, 16, 0, 0);
}

// ---------------- workspace layout (bytes) — proven layout; DP grows within dead wqT region ----------------
#define OFF_QKV  ((size_t)0)                  // [4224][6144] bf16 ; attn alias [4224][4096] bf16
#define OFF_ATTN OFF_QKV
#define OFF_HB   ((size_t)51904512)           // hidden bf16 [4224][4096] (alias qp, then woT)
#define OFF_QP   OFF_HB
#define OFF_WOT  OFF_HB
#define OFF_WQT  ((size_t)86507520)           // wqkvT bf16 [6144][4096] (alias kp/vp/qd/kd/vd after K2)
#define OFF_KP   ((size_t)86507520)
#define OFF_VP   ((size_t)94896128)
#define OFF_QD   ((size_t)103284736)
#define OFF_KD   ((size_t)104333312)
#define OFF_VD   ((size_t)104595456)
#define OFF_DP   ((size_t)104857600)          // decode partials: 512*16*520*4 = 17,039,360 -> ends 121,896,960 < OFF_T
#define OFF_T    ((size_t)136839168)          // T [4160][48] f32
#define OFF_TO   ((size_t)137637888)          // To [4160][16] f32
#define OFF_COS  ((size_t)137904128)
#define OFF_SIN  ((size_t)138428672)          // total 138,953,216 (proven bound)

// ---------------- K0: rope tables ----------------
__global__ void rope_tab_kernel(float* ctab, float* stab) {
    int idx = blockIdx.x * 256 + threadIdx.x;
    if (idx >= 2049 * 64) return;
    int pos = idx >> 6, d = idx & 63;
    float inv = 1.0f / powf(10000.0f, (float)d / 64.0f);
    float f = (float)pos * inv;
    ctab[idx] = cosf(f);
    stab[idx] = sinf(f);
}

// ---------------- Kc: hidden f32 -> bf16 (padded rows zeroed) ----------------
__global__ void conv_hidden_kernel(const float* __restrict__ x, u16* __restrict__ y) {
    int gid = blockIdx.x * 256 + threadIdx.x;
    if (gid >= M_PAD * (HIDDEN / 8)) return;
    size_t base = (size_t)gid * 8;
    int row = gid >> 9;
    usv4 lo, hi;
    if (row < T_TOT) {
        fv4 a = *(const fv4*)(x + base);
        fv4 b = *(const fv4*)(x + base + 4);
        lo[0] = f2b(a[0]); lo[1] = f2b(a[1]); lo[2] = f2b(a[2]); lo[3] = f2b(a[3]);
        hi[0] = f2b(b[0]); hi[1] = f2b(b[1]); hi[2] = f2b(b[2]); hi[3] = f2b(b[3]);
    } else {
        lo[0] = 0; lo[1] = 0; lo[2] = 0; lo[3] = 0;
        hi[0] = 0; hi[1] = 0; hi[2] = 0; hi[3] = 0;
    }
    *(usv4*)(y + base) = lo;
    *(usv4*)(y + base + 4) = hi;
}

// ---------------- Kt: transpose f32 [R][C] -> bf16 [C][R] ----------------
__global__ __launch_bounds__(256) void transpose_f32_bf16_kernel(const float* __restrict__ in,
                                                                 u16* __restrict__ out,
                                                                 int R, int C) {
    __shared__ float tile[64][65];
    int r0 = blockIdx.y * 64, c0 = blockIdx.x * 64;
    int t = threadIdx.x;
    int tr = t >> 4, tc4 = (t & 15) * 4;
#pragma unroll
    for (int it = 0; it < 4; ++it) {
        int r = tr + it * 16;
        fv4 v = *(const fv4*)(in + (size_t)(r0 + r) * C + c0 + tc4);
        tile[r][tc4 + 0] = v[0]; tile[r][tc4 + 1] = v[1];
        tile[r][tc4 + 2] = v[2]; tile[r][tc4 + 3] = v[3];
    }
    __syncthreads();
#pragma unroll
    for (int it = 0; it < 4; ++it) {
        int c = tr + it * 16;
        usv4 st;
        st[0] = f2b(tile[tc4 + 0][c]); st[1] = f2b(tile[tc4 + 1][c]);
        st[2] = f2b(tile[tc4 + 2][c]); st[3] = f2b(tile[tc4 + 3][c]);
        *(usv4*)(out + (size_t)(c0 + c) * R + r0 + tc4) = st;
    }
}

// ---------------- K1: LoRA-A ranks (q,k,v) — LDS-staged, 4 tokens/block ----------------
__global__ __launch_bounds__(256) void lora_a_kernel(const float* __restrict__ x,
                              const float* __restrict__ Aq, const float* __restrict__ Ak,
                              const float* __restrict__ Av,
                              const int* __restrict__ pidx, const int* __restrict__ didx,
                              float* __restrict__ T) {
    __shared__ float xs[4][HIDDEN];
    int t0 = blockIdx.x * 4;
    int tid = threadIdx.x;
    for (int j = tid; j < 4096; j += 256) {
        int tok = j >> 10, off = (j & 1023) * 4;
        *(fv4*)&xs[tok][off] = *(const fv4*)(x + (size_t)(t0 + tok) * HIDDEN + off);
    }
    __syncthreads();
    int w = tid >> 6, lane = tid & 63;
    if (w >= 3) return;
    const float* Ab = (w == 0) ? Aq : (w == 1 ? Ak : Av);
    float acc[4][16];
#pragma unroll
    for (int tk = 0; tk < 4; ++tk)
#pragma unroll
        for (int r = 0; r < 16; ++r) acc[tk][r] = 0.f;
#pragma unroll
    for (int tk = 0; tk < 4; ++tk) {
        int t = t0 + tk;
        int a = (t < TP) ? pidx[t >> 10] : didx[t - TP];
        const float* A = Ab + (size_t)a * HIDDEN * RANK;
        for (int i = 0; i < 64; ++i) {
            int hh = i * 64 + lane;
            float xv = xs[tk][hh];
            const float* Ar = A + (size_t)hh * RANK;
            fv4 a0 = *(const fv4*)Ar, a1 = *(const fv4*)(Ar + 4);
            fv4 a2 = *(const fv4*)(Ar + 8), a3 = *(const fv4*)(Ar + 12);
#pragma unroll
            for (int r = 0; r < 4; ++r) {
                acc[tk][r] += xv * a0[r];
                acc[tk][4 + r] += xv * a1[r];
                acc[tk][8 + r] += xv * a2[r];
                acc[tk][12 + r] += xv * a3[r];
            }
        }
    }
#pragma unroll
    for (int tk = 0; tk < 4; ++tk)
#pragma unroll
        for (int r = 0; r < 16; ++r) {
            float v = acc[tk][r];
            v += __shfl_xor(v, 1); v += __shfl_xor(v, 2); v += __shfl_xor(v, 4);
            v += __shfl_xor(v, 8); v += __shfl_xor(v, 16); v += __shfl_xor(v, 32);
            if (lane == r) T[(size_t)(t0 + tk) * 48 + w * 16 + r] = v;
        }
}

// ---------------- K2/K7: bf16 GEMM, 2-phase dbuf (proven) ----------------
template <int OUT_BF16>
__global__ __launch_bounds__(256) void gemm_bt_kernel(const u16* __restrict__ A,
                                                      const u16* __restrict__ BT,
                                                      void* __restrict__ Cp,
                                                      int Mstore, int N, int K) {
    __shared__ __align__(16) u16 As[2][128 * 32];
    __shared__ __align__(16) u16 Bs[2][128 * 32];
    int tid = threadIdx.x;
    int m0 = blockIdx.y * 128, n0 = blockIdx.x * 128;
    int lane = tid & 63, w = tid >> 6, lr = lane & 15, lg = lane >> 4;
    int wr = w >> 1, wc = w & 1;
    int arow = tid >> 2, acol = (tid & 3) * 8;
    const u16* Ab = A + (size_t)(m0 + arow) * K + acol;
    const u16* Bb = BT + (size_t)(n0 + arow) * K + acol;
    fv4 acc[4][4] = {};
    int nt = K / 32;
#define GSTAGE(buf, kk)                                                             \
    {                                                                               \
        char* Ad = (char*)&As[buf][0] + w * 1024;                                   \
        char* Bd = (char*)&Bs[buf][0] + w * 1024;                                   \
        gload_lds16(Ab + (kk), Ad);                                                 \
        gload_lds16(Ab + (size_t)64 * K + (kk), Ad + 4096);                         \
        gload_lds16(Bb + (kk), Bd);                                                 \
        gload_lds16(Bb + (size_t)64 * K + (kk), Bd + 4096);                         \
    }
    GSTAGE(0, 0)
    __syncthreads();
    int cur = 0;
    for (int t = 0; t < nt; ++t) {
        if (t + 1 < nt) GSTAGE(cur ^ 1, (t + 1) * 32)
        bf16x8 af[4], bf[4];
#pragma unroll
        for (int i = 0; i < 4; ++i) {
            af[i] = *(const bf16x8*)&As[cur][(wr * 64 + i * 16 + lr) * 32 + lg * 8];
            bf[i] = *(const bf16x8*)&Bs[cur][(wc * 64 + i * 16 + lr) * 32 + lg * 8];
        }
#pragma unroll
        for (int mi = 0; mi < 4; ++mi)
#pragma unroll
            for (int ni = 0; ni < 4; ++ni)
                acc[mi][ni] = __builtin_amdgcn_mfma_f32_16x16x32_bf16(af[mi], bf[ni], acc[mi][ni], 0, 0, 0);
        __syncthreads();
        cur ^= 1;
    }
#undef GSTAGE
#pragma unroll
    for (int mi = 0; mi < 4; ++mi)
#pragma unroll
        for (int ni = 0; ni < 4; ++ni) {
            int col = n0 + wc * 64 + ni * 16 + lr;
#pragma unroll
            for (int r = 0; r < 4; ++r) {
                int row = m0 + wr * 64 + mi * 16 + lg * 4 + r;
                if (row < Mstore) {
                    if (OUT_BF16)
                        ((u16*)Cp)[(size_t)row * N + col] = f2b(acc[mi][ni][r]);
                    else
                        ((float*)Cp)[(size_t)row * N + col] = acc[mi][ni][r];
                }
            }
        }
}

// ---------------- K3: LoRA-B add + RoPE + scatter (proven) ----------------
__global__ __launch_bounds__(256) void lorab_rope_scatter_kernel(
    const u16* __restrict__ qkv, const float* __restrict__ T,
    const float* __restrict__ Bq, const float* __restrict__ Bk, const float* __restrict__ Bv,
    const int* __restrict__ pidx, const int* __restrict__ didx,
    const float* __restrict__ ctab, const float* __restrict__ stab,
    u16* __restrict__ qp, u16* __restrict__ kp, u16* __restrict__ vp,
    float* __restrict__ qd, float* __restrict__ kd, float* __restrict__ vd) {
    int t = blockIdx.x;
    __shared__ float Ts[48];
    if (threadIdx.x < 48) Ts[threadIdx.x] = T[(size_t)t * 48 + threadIdx.x];
    __syncthreads();
    bool pre = t < TP;
    int a = pre ? pidx[t >> 10] : didx[t - TP];
    int pos = pre ? (t & 1023) : L_CTX;
    int b = t >> 10;
    int td = t - TP;
    const u16* qrow = qkv + (size_t)t * QKV_DIM;
    for (int p = threadIdx.x; p < 3072; p += 256) {
        if (p < 2048) {  // Q
            int h = p >> 6, d = p & 63;
            int col = h * 128 + d;
            float v1 = b2f(qrow[col]), v2 = b2f(qrow[col + 64]);
            const float* B = Bq + (size_t)a * RANK * Q_DIM;
            float l1 = 0.f, l2 = 0.f;
#pragma unroll
            for (int r = 0; r < 16; ++r) {
                float tv = Ts[r];
                l1 += tv * B[(size_t)r * Q_DIM + col];
                l2 += tv * B[(size_t)r * Q_DIM + col + 64];
            }
            v1 += LORA_SCALE * l1; v2 += LORA_SCALE * l2;
            float c = ctab[pos * 64 + d], s = stab[pos * 64 + d];
            float o1 = v1 * c - v2 * s, o2 = v2 * c + v1 * s;
            if (pre) {
                size_t base = (((size_t)(b * 32 + h)) * 1024 + pos) * 128 + d;
                qp[base] = f2b(o1); qp[base + 64] = f2b(o2);
            } else {
                size_t base = ((size_t)(td * 32 + h)) * 128 + d;
                qd[base] = o1; qd[base + 64] = o2;
            }
        } else if (p < 2560) {  // K
            int pp = p - 2048;
            int h = pp >> 6, d = pp & 63;
            int jc = h * 128 + d;
            int col = Q_DIM + jc;
            float v1 = b2f(qrow[col]), v2 = b2f(qrow[col + 64]);
            const float* B = Bk + (size_t)a * RANK * KV_DIM;
            float l1 = 0.f, l2 = 0.f;
#pragma unroll
            for (int r = 0; r < 16; ++r) {
                float tv = Ts[16 + r];
                l1 += tv * B[(size_t)r * KV_DIM + jc];
                l2 += tv * B[(size_t)r * KV_DIM + jc + 64];
            }
            v1 += LORA_SCALE * l1; v2 += LORA_SCALE * l2;
            float c = ctab[pos * 64 + d], s = stab[pos * 64 + d];
            float o1 = v1 * c - v2 * s, o2 = v2 * c + v1 * s;
            if (pre) {
                size_t base = (((size_t)(b * 8 + h)) * 1024 + pos) * 128 + d;
                kp[base] = f2b(o1); kp[base + 64] = f2b(o2);
            } else {
                size_t base = ((size_t)(td * 8 + h)) * 128 + d;
                kd[base] = o1; kd[base + 64] = o2;
            }
        } else {  // V (no rope)
            int pp = p - 2560;
            int h = pp >> 6, d = pp & 63;
            int jc = h * 128 + d;
            int col = Q_DIM + KV_DIM + jc;
            float v1 = b2f(qrow[col]), v2 = b2f(qrow[col + 64]);
            const float* B = Bv + (size_t)a * RANK * KV_DIM;
            float l1 = 0.f, l2 = 0.f;
#pragma unroll
            for (int r = 0; r < 16; ++r) {
                float tv = Ts[32 + r];
                l1 += tv * B[(size_t)r * KV_DIM + jc];
                l2 += tv * B[(size_t)r * KV_DIM + jc + 64];
            }
            v1 += LORA_SCALE * l1; v2 += LORA_SCALE * l2;
            if (pre) {
                size_t base = (((size_t)(b * 8 + h)) * 1024 + pos) * 128 + d;
                vp[base] = f2b(v1); vp[base + 64] = f2b(v2);
            } else {
                size_t base = ((size_t)(td * 8 + h)) * 128 + d;
                vd[base] = v1; vd[base + 64] = v2;
            }
        }
    }
}

// ---------------- K4: prefill flash attention (round-8 proven) ----------------
__global__ __launch_bounds__(256) void prefill_attn_kernel(const u16* __restrict__ qp,
                                                           const u16* __restrict__ kp,
                                                           const u16* __restrict__ vp,
                                                           u16* __restrict__ attn) {
    int bx = blockIdx.x;
    int qt = (bx & 1) ? (31 - (bx >> 1)) : (bx >> 1);
    int kvh = blockIdx.y, b = blockIdx.z;
    int tid = threadIdx.x, w = tid >> 6, lane = tid & 63, lr = lane & 15, lg = lane >> 4;
    int h = kvh * 4 + w;
    const u16* Q = qp + ((size_t)(b * 32 + h)) * 1024 * 128;
    const u16* K = kp + ((size_t)(b * 8 + kvh)) * 1024 * 128;
    const u16* V = vp + ((size_t)(b * 8 + kvh)) * 1024 * 128;
    int qc0 = qt * 32 + lr, qc1 = qt * 32 + 16 + lr;
    bf16x8 qf0[4], qf1[4];
#pragma unroll
    for (int dc = 0; dc < 4; ++dc) {
        qf0[dc] = *(const bf16x8*)(Q + (size_t)qc0 * 128 + dc * 32 + lg * 8);
        qf1[dc] = *(const bf16x8*)(Q + (size_t)qc1 * 128 + dc * 32 + lg * 8);
    }
    fv4 o0[8] = {}, o1[8] = {};
    float m0 = -INFINITY, l0 = 0.f;
    float m1 = -INFINITY, l1 = 0.f;
    int nkb = qt + 1;
    for (int kb = 0; kb < nkb; ++kb) {
        int k0 = kb * 32;
        fv4 s00 = {}, s10 = {}, s01 = {}, s11 = {};
#pragma unroll
        for (int dc = 0; dc < 4; ++dc) {
            bf16x8 kf0 = *(const bf16x8*)(K + (size_t)(k0 + lr) * 128 + dc * 32 + lg * 8);
            bf16x8 kf1 = *(const bf16x8*)(K + (size_t)(k0 + 16 + lr) * 128 + dc * 32 + lg * 8);
            s00 = __builtin_amdgcn_mfma_f32_16x16x32_bf16(kf0, qf0[dc], s00, 0, 0, 0);
            s10 = __builtin_amdgcn_mfma_f32_16x16x32_bf16(kf1, qf0[dc], s10, 0, 0, 0);
            s01 = __builtin_amdgcn_mfma_f32_16x16x32_bf16(kf0, qf1[dc], s01, 0, 0, 0);
            s11 = __builtin_amdgcn_mfma_f32_16x16x32_bf16(kf1, qf1[dc], s11, 0, 0, 0);
        }
        bf16x8 vf[8];
#pragma unroll
        for (int c = 0; c < 8; ++c)
#pragma unroll
            for (int i = 0; i < 4; ++i) {
                vf[c][i] = __builtin_bit_cast(__bf16, V[(size_t)(k0 + lg * 4 + i) * 128 + c * 16 + lr]);
                vf[c][4 + i] = __builtin_bit_cast(__bf16, V[(size_t)(k0 + 16 + lg * 4 + i) * 128 + c * 16 + lr]);
            }
        bf16x8 pf0, pf1;
        {
            float p0[4], p1[4];
            float lm = -INFINITY;
#pragma unroll
            for (int r = 0; r < 4; ++r) {
                float x = s00[r] * SCALE;
                if (k0 + lg * 4 + r > qc0) x = -INFINITY;
                p0[r] = x; lm = fmaxf(lm, x);
                x = s10[r] * SCALE;
                if (k0 + 16 + lg * 4 + r > qc0) x = -INFINITY;
                p1[r] = x; lm = fmaxf(lm, x);
            }
            lm = fmaxf(lm, __shfl_xor(lm, 16));
            lm = fmaxf(lm, __shfl_xor(lm, 32));
            float mn = fmaxf(m0, lm);
            float sc = __expf(m0 - mn);
            float rs = 0.f;
#pragma unroll
            for (int r = 0; r < 4; ++r) {
                p0[r] = __expf(p0[r] - mn);
                p1[r] = __expf(p1[r] - mn);
                rs += p0[r] + p1[r];
            }
            rs += __shfl_xor(rs, 16);
            rs += __shfl_xor(rs, 32);
            l0 = l0 * sc + rs;
            m0 = mn;
#pragma unroll
            for (int c = 0; c < 8; ++c) o0[c] *= sc;
#pragma unroll
            for (int r = 0; r < 4; ++r) {
                pf0[r] = (__bf16)p0[r];
                pf0[4 + r] = (__bf16)p1[r];
            }
        }
        {
            float p0[4], p1[4];
            float lm = -INFINITY;
#pragma unroll
            for (int r = 0; r < 4; ++r) {
                float x = s01[r] * SCALE;
                if (k0 + lg * 4 + r > qc1) x = -INFINITY;
                p0[r] = x; lm = fmaxf(lm, x);
                x = s11[r] * SCALE;
                if (k0 + 16 + lg * 4 + r > qc1) x = -INFINITY;
                p1[r] = x; lm = fmaxf(lm, x);
            }
            lm = fmaxf(lm, __shfl_xor(lm, 16));
            lm = fmaxf(lm, __shfl_xor(lm, 32));
            float mn = fmaxf(m1, lm);
            float sc = __expf(m1 - mn);
            float rs = 0.f;
#pragma unroll
            for (int r = 0; r < 4; ++r) {
                p0[r] = __expf(p0[r] - mn);
                p1[r] = __expf(p1[r] - mn);
                rs += p0[r] + p1[r];
            }
            rs += __shfl_xor(rs, 16);
            rs += __shfl_xor(rs, 32);
            l1 = l1 * sc + rs;
            m1 = mn;
#pragma unroll
            for (int c = 0; c < 8; ++c) o1[c] *= sc;
#pragma unroll
            for (int r = 0; r < 4; ++r) {
                pf1[r] = (__bf16)p0[r];
                pf1[4 + r] = (__bf16)p1[r];
            }
        }
#pragma unroll
        for (int c = 0; c < 8; ++c) {
            o0[c] = __builtin_amdgcn_mfma_f32_16x16x32_bf16(vf[c], pf0, o0[c], 0, 0, 0);
            o1[c] = __builtin_amdgcn_mfma_f32_16x16x32_bf16(vf[c], pf1, o1[c], 0, 0, 0);
        }
    }
    float inv0 = 1.0f / l0, inv1 = 1.0f / l1;
    size_t trow0 = (size_t)(b * 1024 + qc0) * Q_DIM;
    size_t trow1 = (size_t)(b * 1024 + qc1) * Q_DIM;
#pragma unroll
    for (int c = 0; c < 8; ++c)
#pragma unroll
        for (int r = 0; r < 4; ++r) {
            int feat = h * 128 + c * 16 + lg * 4 + r;
            attn[trow0 + feat] = f2b(o0[c][r] * inv0);
            attn[trow1 + feat] = f2b(o1[c][r] * inv1);
        }
}

// ---------------- decode helpers: rope'd K fragment (f32 cache -> bf16x8) ----------------
template <int FIRST_HALF>
__device__ __forceinline__ bf16x8 krope8(const float* __restrict__ Krow,
                                         const float* __restrict__ ct,
                                         const float* __restrict__ st, int d0) {
    bf16x8 out;
    if (FIRST_HALF) {
        fv4 a0 = *(const fv4*)(Krow + d0), a1 = *(const fv4*)(Krow + d0 + 4);
        fv4 b0 = *(const fv4*)(Krow + d0 + 64), b1 = *(const fv4*)(Krow + d0 + 68);
        fv4 c0 = *(const fv4*)(ct + d0), c1 = *(const fv4*)(ct + d0 + 4);
        fv4 s0 = *(const fv4*)(st + d0), s1 = *(const fv4*)(st + d0 + 4);
#pragma unroll
        for (int i = 0; i < 4; ++i) {
            out[i] = (__bf16)(a0[i] * c0[i] - b0[i] * s0[i]);
            out[4 + i] = (__bf16)(a1[i] * c1[i] - b1[i] * s1[i]);
        }
    } else {
        int dd = d0 - 64;
        fv4 a0 = *(const fv4*)(Krow + d0), a1 = *(const fv4*)(Krow + d0 + 4);
        fv4 b0 = *(const fv4*)(Krow + dd), b1 = *(const fv4*)(Krow + dd + 4);
        fv4 c0 = *(const fv4*)(ct + dd), c1 = *(const fv4*)(ct + dd + 4);
        fv4 s0 = *(const fv4*)(st + dd), s1 = *(const fv4*)(st + dd + 4);
#pragma unroll
        for (int i = 0; i < 4; ++i) {
            out[i] = (__bf16)(a0[i] * c0[i] + b0[i] * s0[i]);
            out[4 + i] = (__bf16)(a1[i] * c1[i] + b1[i] * s1[i]);
        }
    }
    return out;
}

// ---------------- K5: decode attention — MFMA over cache keys; 16 splits x 128 keys ----------------
// Structure mirrors prefill (proven fragment mapping). Q group (4 heads) replicated into
// the 16 B-cols via lr&3; only cols 0..3 consumed. No causal mask (all cache keys valid).
__global__ __launch_bounds__(128) void decode_attn_kernel(const float* __restrict__ kc,
                                                          const float* __restrict__ vc,
                                                          const float* __restrict__ qd,
                                                          const float* __restrict__ ctab,
                                                          const float* __restrict__ stab,
                                                          float* __restrict__ dp) {
    int blk = blockIdx.x;                       // 0..4095
    int bk = blk >> 3;                          // b*8+kvh
    int b = bk >> 3, kvh = bk & 7;
    int wv = threadIdx.x >> 6, lane = threadIdx.x & 63;
    int s = (blk & 7) * 2 + wv;                 // split 0..15
    int lr = lane & 15, lg = lane >> 4;
    const float* Qrow = qd + ((size_t)(b * 32 + kvh * 4 + (lr & 3))) * 128;
    bf16x8 qf[4];
#pragma unroll
    for (int dc = 0; dc < 4; ++dc) {
        int d0 = dc * 32 + lg * 8;
        fv4 q0 = *(const fv4*)(Qrow + d0), q1 = *(const fv4*)(Qrow + d0 + 4);
#pragma unroll
        for (int i = 0; i < 4; ++i) {
            qf[dc][i] = (__bf16)q0[i];
            qf[dc][4 + i] = (__bf16)q1[i];
        }
    }
    fv4 o[8] = {};
    float m = -INFINITY, l = 0.f;
    int kbase = s * DSPLIT_LEN;
    for (int t = 0; t < 4; ++t) {
        int k0 = kbase + t * 32;
        int key0 = k0 + lr, key1 = k0 + 16 + lr;
        const float* K0 = kc + (((size_t)b * L_CTX + key0) * 8 + kvh) * 128;
        const float* K1 = kc + (((size_t)b * L_CTX + key1) * 8 + kvh) * 128;
        const float* ct0 = ctab + key0 * 64;
        const float* st0 = stab + key0 * 64;
        const float* ct1 = ctab + key1 * 64;
        const float* st1 = stab + key1 * 64;
        fv4 s0 = {}, s1 = {};
#pragma unroll
        for (int dc = 0; dc < 4; ++dc) {
            int d0 = dc * 32 + lg * 8;
            bf16x8 kf0, kf1;
            if (dc < 2) {
                kf0 = krope8<1>(K0, ct0, st0, d0);
                kf1 = krope8<1>(K1, ct1, st1, d0);
            } else {
                kf0 = krope8<0>(K0, ct0, st0, d0);
                kf1 = krope8<0>(K1, ct1, st1, d0);
            }
            s0 = __builtin_amdgcn_mfma_f32_16x16x32_bf16(kf0, qf[dc], s0, 0, 0, 0);
            s1 = __builtin_amdgcn_mfma_f32_16x16x32_bf16(kf1, qf[dc], s1, 0, 0, 0);
        }
        // V fragments (f32 cache, key stride 1024 floats)
        const float* Vb = vc + (((size_t)b * L_CTX + k0) * 8 + kvh) * 128;
        bf16x8 vf[8];
#pragma unroll
        for (int c = 0; c < 8; ++c)
#pragma unroll
            for (int i = 0; i < 4; ++i) {
                vf[c][i] = (__bf16)Vb[(size_t)(lg * 4 + i) * 1024 + c * 16 + lr];
                vf[c][4 + i] = (__bf16)Vb[(size_t)(16 + lg * 4 + i) * 1024 + c * 16 + lr];
            }
        // online softmax (no mask), 4 shuffles per 32 keys
        float p0[4], p1[4];
        float lm = -INFINITY;
#pragma unroll
        for (int r = 0; r < 4; ++r) {
            float x = s0[r] * SCALE;
            p0[r] = x; lm = fmaxf(lm, x);
            x = s1[r] * SCALE;
            p1[r] = x; lm = fmaxf(lm, x);
        }
        lm = fmaxf(lm, __shfl_xor(lm, 16));
        lm = fmaxf(lm, __shfl_xor(lm, 32));
        float mn = fmaxf(m, lm);
        float sc = __expf(m - mn);
        float rs = 0.f;
#pragma unroll
        for (int r = 0; r < 4; ++r) {
            p0[r] = __expf(p0[r] - mn);
            p1[r] = __expf(p1[r] - mn);
            rs += p0[r] + p1[r];
        }
        rs += __shfl_xor(rs, 16);
        rs += __shfl_xor(rs, 32);
        l = l * sc + rs;
        m = mn;
#pragma unroll
        for (int c = 0; c < 8; ++c) o[c] *= sc;
        bf16x8 pf;
#pragma unroll
        for (int r = 0; r < 4; ++r) {
            pf[r] = (__bf16)p0[r];
            pf[4 + r] = (__bf16)p1[r];
        }
#pragma unroll
        for (int c = 0; c < 8; ++c)
            o[c] = __builtin_amdgcn_mfma_f32_16x16x32_bf16(vf[c], pf, o[c], 0, 0, 0);
    }
    // write partial: valid q cols are 0..3 (lr<4); d = c*16 + lg*4 + r
    size_t base = ((size_t)(bk * DNSPLIT + s)) * DP_STRIDE;
    if (lr < 4) {
#pragma unroll
        for (int c = 0; c < 8; ++c)
#pragma unroll
            for (int r = 0; r < 4; ++r)
                dp[base + 8 + lr * 128 + c * 16 + lg * 4 + r] = o[c][r];
        if (lg == 0) { dp[base + lr] = m; dp[base + 4 + lr] = l; }
    }
}

// ---------------- K5b: decode merge (16 splits + new-token key) ----------------
__global__ __launch_bounds__(256) void decode_merge_kernel(const float* __restrict__ dp,
                                                           const float* __restrict__ qd,
                                                           const float* __restrict__ kd,
                                                           const float* __restrict__ vd,
                                                           u16* __restrict__ attn) {
    int bk = blockIdx.x;                 // 0..511
    int b = bk >> 3, kvh = bk & 7;
    int g = threadIdx.x >> 6, lane = threadIdx.x & 63;
    size_t qb = ((size_t)(b * 32 + kvh * 4 + g)) * 128;
    float q1 = qd[qb + lane], q2 = qd[qb + 64 + lane];
    size_t kb = ((size_t)(b * 8 + kvh)) * 128;
    float k1 = kd[kb + lane], k2 = kd[kb + 64 + lane];
    float v1 = vd[kb + lane], v2 = vd[kb + 64 + lane];
    float part = q1 * k1 + q2 * k2;
#pragma unroll
    for (int off = 32; off; off >>= 1) part += __shfl_xor(part, off);
    float snew = part * SCALE;
    float M = snew;
#pragma unroll
    for (int s = 0; s < DNSPLIT; ++s)
        M = fmaxf(M, dp[((size_t)(bk * DNSPLIT + s)) * DP_STRIDE + g]);
    float L = 0.f, O1 = 0.f, O2 = 0.f;
#pragma unroll
    for (int s = 0; s < DNSPLIT; ++s) {
        size_t base = ((size_t)(bk * DNSPLIT + s)) * DP_STRIDE;
        float e = __expf(dp[base + g] - M);
        L += dp[base + 4 + g] * e;
        O1 += dp[base + 8 + g * 128 + lane] * e;
        O2 += dp[base + 8 + g * 128 + 64 + lane] * e;
    }
    float en = __expf(snew - M);
    L += en; O1 += en * v1; O2 += en * v2;
    size_t orow = (size_t)(TP + b) * Q_DIM + (kvh * 4 + g) * 128;
    attn[orow + lane] = f2b(O1 / L);
    attn[orow + 64 + lane] = f2b(O2 / L);
}

// ---------------- K6: LoRA-A for output — LDS-staged, 4 tokens/block, 1 wave ----------------
__global__ __launch_bounds__(64) void lora_o_a_kernel(const u16* __restrict__ attn,
                                const float* __restrict__ Ao,
                                const int* __restrict__ pidx, const int* __restrict__ didx,
                                float* __restrict__ To) {
    __shared__ float xs[4][HIDDEN];
    int t0 = blockIdx.x * 4;
    int lane = threadIdx.x;
    for (int j = lane; j < 4096; j += 64) {
        int tok = j >> 10, off = (j & 1023) * 4;
        usv4 v = *(const usv4*)(attn + (size_t)(t0 + tok) * Q_DIM + off);
        xs[tok][off] = b2f(v[0]); xs[tok][off + 1] = b2f(v[1]);
        xs[tok][off + 2] = b2f(v[2]); xs[tok][off + 3] = b2f(v[3]);
    }
    __syncthreads();
    float acc[4][16];
#pragma unroll
    for (int tk = 0; tk < 4; ++tk)
#pragma unroll
        for (int r = 0; r < 16; ++r) acc[tk][r] = 0.f;
#pragma unroll
    for (int tk = 0; tk < 4; ++tk) {
        int t = t0 + tk;
        int a = (t < TP) ? pidx[t >> 10] : didx[t - TP];
        const float* A = Ao + (size_t)a * Q_DIM * RANK;
        for (int i = 0; i < 64; ++i) {
            int hh = i * 64 + lane;
            float xv = xs[tk][hh];
            const float* Ar = A + (size_t)hh * RANK;
            fv4 a0 = *(const fv4*)Ar, a1 = *(const fv4*)(Ar + 4);
            fv4 a2 = *(const fv4*)(Ar + 8), a3 = *(const fv4*)(Ar + 12);
#pragma unroll
            for (int r = 0; r < 4; ++r) {
                acc[tk][r] += xv * a0[r];
                acc[tk][4 + r] += xv * a1[r];
                acc[tk][8 + r] += xv * a2[r];
                acc[tk][12 + r] += xv * a3[r];
            }
        }
    }
#pragma unroll
    for (int tk = 0; tk < 4; ++tk)
#pragma unroll
        for (int r = 0; r < 16; ++r) {
            float v = acc[tk][r];
            v += __shfl_xor(v, 1); v += __shfl_xor(v, 2); v += __shfl_xor(v, 4);
            v += __shfl_xor(v, 8); v += __shfl_xor(v, 16); v += __shfl_xor(v, 32);
            if (lane == r) To[(size_t)(t0 + tk) * RANK + r] = v;
        }
}

// ---------------- K8: final LoRA-B(O) add (proven) ----------------
__global__ void final_lora_add_kernel(float* __restrict__ out, const float* __restrict__ To,
                                      const float* __restrict__ Bo,
                                      const int* __restrict__ pidx, const int* __restrict__ didx) {
    int gid = blockIdx.x * 256 + threadIdx.x;
    if (gid >= T_TOT * HIDDEN) return;
    int t = gid >> 12, j = gid & 4095;
    int a = (t < TP) ? pidx[t >> 10] : didx[t - TP];
    const float* B = Bo + (size_t)a * RANK * HIDDEN;
    const float* Tr = To + (size_t)t * RANK;
    float acc = 0.f;
#pragma unroll
    for (int r = 0; r < 16; ++r) acc += Tr[r] * B[(size_t)r * HIDDEN + j];
    out[gid] += LORA_SCALE * acc;
}

// ---------------- launch ----------------
extern "C" void kernel_launch(void* const* d_in, const int* in_sizes, int n_in,
                              void* d_out, int out_size, void* d_ws, size_t ws_size,
                              hipStream_t stream) {
    const float* hidden = (const float*)d_in[0];
    const float* w_qkv = (const float*)d_in[1];
    const float* w_o = (const float*)d_in[2];
    const float* k_cache = (const float*)d_in[3];
    const float* v_cache = (const float*)d_in[4];
    const float* Aq = (const float*)d_in[5];
    const float* Bq = (const float*)d_in[6];
    const float* Ak = (const float*)d_in[7];
    const float* Bk = (const float*)d_in[8];
    const float* Av = (const float*)d_in[9];
    const float* Bv = (const float*)d_in[10];
    const float* Ao = (const float*)d_in[11];
    const float* Bo = (const float*)d_in[12];
    const int* pidx = (const int*)d_in[13];
    const int* didx = (const int*)d_in[14];
    float* out = (float*)d_out;

    char* ws = (char*)d_ws;
    u16* qkv = (u16*)(ws + OFF_QKV);
    u16* attn = (u16*)(ws + OFF_ATTN);
    u16* hb = (u16*)(ws + OFF_HB);
    u16* wqT = (u16*)(ws + OFF_WQT);
    u16* woT = (u16*)(ws + OFF_WOT);
    float* T = (float*)(ws + OFF_T);
    u16* qp = (u16*)(ws + OFF_QP);
    u16* kp = (u16*)(ws + OFF_KP);
    u16* vp = (u16*)(ws + OFF_VP);
    float* qd = (float*)(ws + OFF_QD);
    float* kd = (float*)(ws + OFF_KD);
    float* vd = (float*)(ws + OFF_VD);
    float* dp = (float*)(ws + OFF_DP);
    float* To = (float*)(ws + OFF_TO);
    float* ctab = (float*)(ws + OFF_COS);
    float* stab = (float*)(ws + OFF_SIN);

    rope_tab_kernel<<<513, 256, 0, stream>>>(ctab, stab);
    conv_hidden_kernel<<<(M_PAD * (HIDDEN / 8) + 255) / 256, 256, 0, stream>>>(hidden, hb);
    transpose_f32_bf16_kernel<<<dim3(QKV_DIM / 64, HIDDEN / 64), 256, 0, stream>>>(w_qkv, wqT, HIDDEN, QKV_DIM);
    lora_a_kernel<<<T_TOT / 4, 256, 0, stream>>>(hidden, Aq, Ak, Av, pidx, didx, T);
    gemm_bt_kernel<1><<<dim3(QKV_DIM / 128, M_PAD / 128), 256, 0, stream>>>(hb, wqT, qkv, M_PAD, QKV_DIM, HIDDEN);
    lorab_rope_scatter_kernel<<<T_TOT, 256, 0, stream>>>(qkv, T, Bq, Bk, Bv, pidx, didx,
                                                         ctab, stab, qp, kp, vp, qd, kd, vd);
    prefill_attn_kernel<<<dim3(32, 8, 4), 256, 0, stream>>>(qp, kp, vp, attn);
    decode_attn_kernel<<<4096, 128, 0, stream>>>(k_cache, v_cache, qd, ctab, stab, dp);
    decode_merge_kernel<<<512, 256, 0, stream>>>(dp, qd, kd, vd, attn);
    transpose_f32_bf16_kernel<<<dim3(HIDDEN / 64, Q_DIM / 64), 256, 0, stream>>>(w_o, woT, Q_DIM, HIDDEN);
    lora_o_a_kernel<<<T_TOT / 4, 64, 0, stream>>>(attn, Ao, pidx, didx, To);
    gemm_bt_kernel<0><<<dim3(HIDDEN / 128, M_PAD / 128), 256, 0, stream>>>(attn, woT, out, T_TOT, HIDDEN, Q_DIM);
    final_lora_add_kernel<<<(T_TOT * HIDDEN + 255) / 256, 256, 0, stream>>>(out, To, Bo, pidx, didx);
}